// Round 2
// baseline (3708.094 us; speedup 1.0000x reference)
//
#include <hip/hip_runtime.h>
#include <cstdint>
#include <cstddef>

// Problem constants (VectorQuantizer: L=32768, D=64, N_E=16384, beta=0.25)
#define L_TOK 32768
#define D_DIM 64
#define NE    16384
#define GCHUNKS 4              // N split across grid
#define NPB   (NE / GCHUNKS)   // 4096 n per block
#define BN    128              // n per LDS stage chunk
#define BROWS 128              // rows per block (8 waves x 16)

typedef unsigned short ushort_t;
typedef __attribute__((ext_vector_type(8))) short bf16x8;
typedef __attribute__((ext_vector_type(4))) float f32x4;

// ---- ws layout (bytes) ----
#define WS_EHI  0                                   // 2 MB  e_hi permuted
#define WS_ELO  (2u<<20)                            // 2 MB  e_lo permuted
#define WS_ESQ  (4u<<20)                            // 64 KB esq (np-exact fp32)
#define WS_CAND ((4u<<20) + 65536u)                 // 2 MB  cand[4][L][4] int
#define WS_PART ((4u<<20) + 65536u + (2u<<20))      // 2 KB  loss partials

__device__ __forceinline__ void bf16_split(float v, ushort_t& hs, ushort_t& ls) {
  unsigned u  = __float_as_uint(v);
  unsigned ur = u + 0x7fffu + ((u >> 16) & 1u);      // RNE to bf16
  hs = (ushort_t)(ur >> 16);
  float hf = __uint_as_float(ur & 0xffff0000u);
  float r  = v - hf;                                  // exact residual
  unsigned u2  = __float_as_uint(r);
  unsigned ur2 = u2 + 0x7fffu + ((u2 >> 16) & 1u);
  ls = (ushort_t)(ur2 >> 16);
}

// numpy pairwise_sum emulation for n=64 contiguous fp32 (scalar 8-acc path):
// r[j] = ((((((a[j]+a[j+8])+a[j+16])+...)+a[j+56];  res = ((r0+r1)+(r2+r3))+((r4+r5)+(r6+r7))
// `a` is this lane's element (lane k holds a[k]); all lanes return the sum.
__device__ __forceinline__ float np_sum64(float a) {
  int j = threadIdx.x & 7;
  float r = __shfl(a, j);
  #pragma unroll
  for (int m = 1; m < 8; ++m) r += __shfl(a, j + 8 * m);
  float s0 = __shfl(r, 0), s1 = __shfl(r, 1), s2 = __shfl(r, 2), s3 = __shfl(r, 3);
  float s4 = __shfl(r, 4), s5 = __shfl(r, 5), s6 = __shfl(r, 6), s7 = __shfl(r, 7);
  return ((s0 + s1) + (s2 + s3)) + ((s4 + s5) + (s6 + s7));
}

// Fragment-permuted index (in ushorts) for element (n, k) — LDS staging order
// equals MFMA B-fragment consumption order (conflict-free ds_read_b128).
__device__ __forceinline__ int perm_off(int n, int k) {
  int tile = n >> 4, c = n & 15, s = k >> 5, q = (k >> 3) & 3, j = k & 7;
  return tile * 1024 + s * 512 + (q * 16 + c) * 8 + j;
}

// ---------------- kernel 1: prep embedding (hi/lo split + np-exact esq) ------
__global__ __launch_bounds__(256) void vq_prep_e(const float* __restrict__ e,
                                                 ushort_t* __restrict__ ehi,
                                                 ushort_t* __restrict__ elo,
                                                 float* __restrict__ esqg) {
  int wave = threadIdx.x >> 6, lane = threadIdx.x & 63;
  int row = blockIdx.x * 4 + wave;            // one wave per embedding row
  float v = e[(size_t)row * D_DIM + lane];
  ushort_t hs, ls;
  bf16_split(v, hs, ls);
  int off = perm_off(row, lane);
  ehi[off] = hs;
  elo[off] = ls;
  float esq = np_sum64(v * v);                // numpy-bit-exact sum(e*e, axis=1)
  if (lane == 0) esqg[row] = esq;
}

// ---------------- kernel 2: fused distance + per-row top-k sieve -------------
// grid = dim3(GCHUNKS, L/BROWS), block = 512 (8 waves x 16 rows each)
__global__ __launch_bounds__(512, 4) void vq_argmin(const float* __restrict__ z,
                                                    const ushort_t* __restrict__ ehi,
                                                    const ushort_t* __restrict__ elo,
                                                    const float* __restrict__ esqg,
                                                    int* __restrict__ cand) {
  __shared__ __align__(16) unsigned char smem[49152]; // staging 33280B / merge 49152B
  ushort_t* s_ehi = (ushort_t*)smem;
  ushort_t* s_elo = (ushort_t*)(smem + 16384);
  float*    s_esq = (float*)(smem + 32768);

  const int tid = threadIdx.x;
  const int wave = tid >> 6, lane = tid & 63;
  const int q = lane >> 4, c = lane & 15;
  const int row0 = blockIdx.y * BROWS + wave * 16;
  const int nbase = blockIdx.x * NPB;

  // A fragments (z rows) split hi/lo in-register. A[m=lane&15][k=q*8+j]
  const float* zr = z + (size_t)(row0 + c) * D_DIM;
  float4 a0 = *(const float4*)(zr + q * 8);
  float4 a1 = *(const float4*)(zr + q * 8 + 4);
  float4 a2 = *(const float4*)(zr + 32 + q * 8);
  float4 a3 = *(const float4*)(zr + 32 + q * 8 + 4);
  bf16x8 zh0, zl0, zh1, zl1;
  {
    float v0[8] = {a0.x, a0.y, a0.z, a0.w, a1.x, a1.y, a1.z, a1.w};
    float v1[8] = {a2.x, a2.y, a2.z, a2.w, a3.x, a3.y, a3.z, a3.w};
    #pragma unroll
    for (int j = 0; j < 8; ++j) {
      ushort_t h, l;
      bf16_split(v0[j], h, l); zh0[j] = (short)h; zl0[j] = (short)l;
      bf16_split(v1[j], h, l); zh1[j] = (short)h; zl1[j] = (short)l;
    }
  }

  // per-(acc row r) top-3 tracking
  float m0[4], m1[4], m2[4];
  int   i0[4], i1[4], i2[4];
  #pragma unroll
  for (int r = 0; r < 4; ++r) {
    m0[r] = 3.4e38f; m1[r] = 3.4e38f; m2[r] = 3.4e38f;
    i0[r] = 0; i1[r] = 0; i2[r] = 0;
  }

  for (int cb = 0; cb < NPB / BN; ++cb) {
    int nch = nbase + cb * BN;
    __syncthreads();   // previous chunk's LDS reads done
    {
      const uint4* gh = ((const uint4*)ehi) + (size_t)nch * 8;
      const uint4* gl = ((const uint4*)elo) + (size_t)nch * 8;
      uint4 h0 = gh[tid], h1 = gh[tid + 512];
      uint4 l0 = gl[tid], l1 = gl[tid + 512];
      ((uint4*)s_ehi)[tid] = h0; ((uint4*)s_ehi)[tid + 512] = h1;
      ((uint4*)s_elo)[tid] = l0; ((uint4*)s_elo)[tid + 512] = l1;
      if (tid < BN) s_esq[tid] = 0.5f * esqg[nch + tid];  // sieve score only
    }
    __syncthreads();

    #pragma unroll
    for (int t = 0; t < BN / 16; ++t) {
      const bf16x8 bh0 = *(const bf16x8*)(s_ehi + t * 1024 + lane * 8);
      const bf16x8 bh1 = *(const bf16x8*)(s_ehi + t * 1024 + 512 + lane * 8);
      const bf16x8 bl0 = *(const bf16x8*)(s_elo + t * 1024 + lane * 8);
      const bf16x8 bl1 = *(const bf16x8*)(s_elo + t * 1024 + 512 + lane * 8);
      f32x4 accA = {0.f, 0.f, 0.f, 0.f}, accB = accA, accC = accA;
      accA = __builtin_amdgcn_mfma_f32_16x16x32_bf16(zh0, bh0, accA, 0, 0, 0);
      accB = __builtin_amdgcn_mfma_f32_16x16x32_bf16(zh0, bl0, accB, 0, 0, 0);
      accC = __builtin_amdgcn_mfma_f32_16x16x32_bf16(zl0, bh0, accC, 0, 0, 0);
      accA = __builtin_amdgcn_mfma_f32_16x16x32_bf16(zh1, bh1, accA, 0, 0, 0);
      accB = __builtin_amdgcn_mfma_f32_16x16x32_bf16(zh1, bl1, accB, 0, 0, 0);
      accC = __builtin_amdgcn_mfma_f32_16x16x32_bf16(zl1, bh1, accC, 0, 0, 0);
      float esqv = s_esq[t * 16 + c];
      int n = nch + t * 16 + c;
      #pragma unroll
      for (int r = 0; r < 4; ++r) {
        float dot = (accA[r] + accB[r]) + accC[r];
        float d = esqv - dot;                  // ~ exact_d/2 + O(5e-9)
        bool l0 = d < m0[r], l1 = d < m1[r], l2 = d < m2[r];
        m2[r] = l2 ? (l1 ? m1[r] : d) : m2[r];
        i2[r] = l2 ? (l1 ? i1[r] : n) : i2[r];
        m1[r] = l1 ? (l0 ? m0[r] : d) : m1[r];
        i1[r] = l1 ? (l0 ? i0[r] : n) : i1[r];
        m0[r] = l0 ? d : m0[r];
        i0[r] = l0 ? n : i0[r];
      }
    }
  }

  // merge 16 lanes' top-3 -> per-row top-4 for this chunk
  __syncthreads();
  uint2* s_m = (uint2*)smem;                   // [128 rows][16 c][3]
  #pragma unroll
  for (int r = 0; r < 4; ++r) {
    int rowidx = wave * 16 + q * 4 + r;        // C layout: row = q*4 + reg
    int base = (rowidx * 16 + c) * 3;
    uint2 e0; e0.x = __float_as_uint(m0[r]); e0.y = (unsigned)i0[r];
    uint2 e1; e1.x = __float_as_uint(m1[r]); e1.y = (unsigned)i1[r];
    uint2 e2; e2.x = __float_as_uint(m2[r]); e2.y = (unsigned)i2[r];
    s_m[base + 0] = e0; s_m[base + 1] = e1; s_m[base + 2] = e2;
  }
  __syncthreads();
  if (tid < BROWS) {
    float M[4] = {3.4e38f, 3.4e38f, 3.4e38f, 3.4e38f};
    int   I[4] = {0, 0, 0, 0};
    for (int cc = 0; cc < 48; ++cc) {
      uint2 en = s_m[tid * 48 + cc];
      float v = __uint_as_float(en.x); int id = (int)en.y;
      bool l0 = v < M[0], l1 = v < M[1], l2 = v < M[2], l3 = v < M[3];
      M[3] = l3 ? (l2 ? M[2] : v) : M[3];  I[3] = l3 ? (l2 ? I[2] : id) : I[3];
      M[2] = l2 ? (l1 ? M[1] : v) : M[2];  I[2] = l2 ? (l1 ? I[1] : id) : I[2];
      M[1] = l1 ? (l0 ? M[0] : v) : M[1];  I[1] = l1 ? (l0 ? I[0] : id) : I[1];
      M[0] = l0 ? v : M[0];                I[0] = l0 ? id : I[0];
    }
    int grow = blockIdx.y * BROWS + tid;
    int* cp = cand + ((size_t)blockIdx.x * L_TOK + grow) * 4;
    cp[0] = I[0]; cp[1] = I[1]; cp[2] = I[2]; cp[3] = I[3];
  }
}

// ------- kernel 3: np-fp32-exact rescore of 16 candidates, outputs ----------
__global__ __launch_bounds__(256) void vq_refine(const float* __restrict__ z,
                                                 const float* __restrict__ e,
                                                 const float* __restrict__ esqg,
                                                 const int* __restrict__ cand,
                                                 float* __restrict__ out,
                                                 double* __restrict__ partials) {
  const int tid = threadIdx.x;
  const int wave = tid >> 6, lane = tid & 63;
  __shared__ double sp[4];
  double wl = 0.0;
  for (int it = 0; it < 32; ++it) {
    int row = blockIdx.x * 128 + it * 4 + wave;
    float zf = z[(size_t)row * D_DIM + lane];
    float zsq = np_sum64(zf * zf);             // numpy-bit-exact sum(z*z, axis=1)
    float bestd = 3.4e38f; int bi = 0x7fffffff; float be = 0.f;
    #pragma unroll
    for (int cc = 0; cc < 16; ++cc) {
      int idx = cand[((size_t)(cc >> 2) * L_TOK + row) * 4 + (cc & 3)];
      float ef = e[(size_t)idx * D_DIM + lane];
      double p = (double)zf * (double)ef;
      #pragma unroll
      for (int o = 32; o; o >>= 1) p += __shfl_xor(p, o);
      // emulate np fp32: d = fl32( fl32(zsq + esq) - fl32(2*dot) )
      float t2 = (float)(2.0 * p);
      float T1 = zsq + esqg[idx];
      float d = T1 - t2;
      bool better = (d < bestd) || (d == bestd && idx < bi);  // first-min tie-break
      if (better) { bestd = d; bi = idx; be = ef; }
    }
    // straight-through output, fp32 op order: z + (z_q - z)
    out[(size_t)row * D_DIM + lane] = zf + (be - zf);
    if (lane == 0) out[(size_t)L_TOK * D_DIM + 1 + row] = (float)bi;
    // loss term in fp64 (threshold is loose)
    double df = (double)be - (double)zf;
    double s = df * df;
    #pragma unroll
    for (int o = 32; o; o >>= 1) s += __shfl_xor(s, o);
    wl += s;
  }
  if (lane == 0) sp[wave] = wl;
  __syncthreads();
  if (tid == 0) partials[blockIdx.x] = sp[0] + sp[1] + sp[2] + sp[3];
}

// ---------------- kernel 4: finalize loss ------------------------------------
__global__ __launch_bounds__(256) void vq_loss(const double* __restrict__ partials,
                                               float* __restrict__ out) {
  int tid = threadIdx.x;
  double v = partials[tid];
  #pragma unroll
  for (int o = 32; o; o >>= 1) v += __shfl_xor(v, o);
  __shared__ double sp[4];
  if ((tid & 63) == 0) sp[tid >> 6] = v;
  __syncthreads();
  if (tid == 0) {
    double tot = sp[0] + sp[1] + sp[2] + sp[3];
    // loss = beta*mean + mean = 1.25 * mean((z_q - z)^2)
    out[(size_t)L_TOK * D_DIM] = (float)(1.25 * tot / (double)((size_t)L_TOK * D_DIM));
  }
}

extern "C" void kernel_launch(void* const* d_in, const int* in_sizes, int n_in,
                              void* d_out, int out_size, void* d_ws, size_t ws_size,
                              hipStream_t stream) {
  const float* z = (const float*)d_in[0];       // (32768, 64) fp32
  const float* e = (const float*)d_in[1];       // (16384, 64) fp32
  float* out = (float*)d_out;                   // [z_q_st | loss | indices-as-f32]
  char* ws = (char*)d_ws;                       // needs ~6.2 MB

  ushort_t* ehi   = (ushort_t*)(ws + WS_EHI);
  ushort_t* elo   = (ushort_t*)(ws + WS_ELO);
  float*    esqg  = (float*)(ws + WS_ESQ);
  int*      cand  = (int*)(ws + WS_CAND);
  double*   parts = (double*)(ws + WS_PART);

  vq_prep_e<<<NE / 4, 256, 0, stream>>>(e, ehi, elo, esqg);
  vq_argmin<<<dim3(GCHUNKS, L_TOK / BROWS), 512, 0, stream>>>(z, ehi, elo, esqg, cand);
  vq_refine<<<L_TOK / 128, 256, 0, stream>>>(z, e, esqg, cand, out, parts);
  vq_loss<<<1, 256, 0, stream>>>(parts, out);
}

// Round 3
// 562.025 us; speedup vs baseline: 6.5977x; 6.5977x over previous
//
#include <hip/hip_runtime.h>
#include <cstdint>
#include <cstddef>

// Problem constants (VectorQuantizer: L=32768, D=64, N_E=16384, beta=0.25)
#define L_TOK 32768
#define D_DIM 64
#define NE    16384
#define GCHUNKS 4              // N split across grid
#define NPB   (NE / GCHUNKS)   // 4096 n per block
#define BN    128              // n per LDS stage chunk
#define BROWS 128              // rows per block (8 waves x 16)

#define SCALE_F 16777216.0f    // 2^24 (exact fp32 scaling)
#define KBIAS   131072         // 2^17

typedef unsigned short ushort_t;
typedef __attribute__((ext_vector_type(8))) short bf16x8;
typedef __attribute__((ext_vector_type(4))) float f32x4;

// ---- ws layout (bytes) ----
#define WS_EHI  0                                   // 2 MB  e_hi permuted
#define WS_ELO  (2u<<20)                            // 2 MB  e_lo permuted
#define WS_ESQ  (4u<<20)                            // 64 KB esq (np-exact fp32)
#define WS_ESQS ((4u<<20) + 65536u)                 // 64 KB esq*0.5*2^24 (sieve)
#define WS_CAND ((4u<<20) + 131072u)                // 2 MB  cand[4][L][4] int
#define WS_PART ((4u<<20) + 131072u + (2u<<20))     // 2 KB  loss partials

__device__ __forceinline__ void bf16_split(float v, ushort_t& hs, ushort_t& ls) {
  unsigned u  = __float_as_uint(v);
  unsigned ur = u + 0x7fffu + ((u >> 16) & 1u);      // RNE to bf16
  hs = (ushort_t)(ur >> 16);
  float hf = __uint_as_float(ur & 0xffff0000u);
  float r  = v - hf;                                  // exact residual
  unsigned u2  = __float_as_uint(r);
  unsigned ur2 = u2 + 0x7fffu + ((u2 >> 16) & 1u);
  ls = (ushort_t)(ur2 >> 16);
}

// numpy pairwise_sum emulation for n=64 contiguous fp32 (scalar 8-acc path).
__device__ __forceinline__ float np_sum64(float a) {
  int j = threadIdx.x & 7;
  float r = __shfl(a, j);
  #pragma unroll
  for (int m = 1; m < 8; ++m) r += __shfl(a, j + 8 * m);
  float s0 = __shfl(r, 0), s1 = __shfl(r, 1), s2 = __shfl(r, 2), s3 = __shfl(r, 3);
  float s4 = __shfl(r, 4), s5 = __shfl(r, 5), s6 = __shfl(r, 6), s7 = __shfl(r, 7);
  return ((s0 + s1) + (s2 + s3)) + ((s4 + s5) + (s6 + s7));
}

// Fragment-permuted index (in ushorts) for element (n, k) — LDS staging order
// equals MFMA B-fragment consumption order (conflict-free ds_read_b128).
__device__ __forceinline__ int perm_off(int n, int k) {
  int tile = n >> 4, c = n & 15, s = k >> 5, q = (k >> 3) & 3, j = k & 7;
  return tile * 1024 + s * 512 + (q * 16 + c) * 8 + j;
}

// ---------------- kernel 1: prep embedding (hi/lo split + esq variants) ------
__global__ __launch_bounds__(256) void vq_prep_e(const float* __restrict__ e,
                                                 ushort_t* __restrict__ ehi,
                                                 ushort_t* __restrict__ elo,
                                                 float* __restrict__ esqg,
                                                 float* __restrict__ esqs) {
  int wave = threadIdx.x >> 6, lane = threadIdx.x & 63;
  int row = blockIdx.x * 4 + wave;            // one wave per embedding row
  float v = e[(size_t)row * D_DIM + lane];
  ushort_t hs, ls;
  bf16_split(v, hs, ls);
  int off = perm_off(row, lane);
  ehi[off] = hs;
  elo[off] = ls;
  float esq = np_sum64(v * v);                // numpy-bit-exact sum(e*e, axis=1)
  if (lane == 0) {
    esqg[row] = esq;                          // for the exact rescore
    esqs[row] = (esq * 0.5f) * SCALE_F;       // pre-scaled sieve constant (exact)
  }
}

// ---------------- kernel 2: fused distance + per-row top-k sieve -------------
// grid = dim3(GCHUNKS, L/BROWS), block = 512 (8 waves x 16 rows each)
// Packed sort-key: ((int(d*2^24) + 2^17) << 14) | n   (d = esq/2 - <z,e>)
//   monotone in d (6e-8 buckets << 7.6e-6 np-fp32 window handled by refine),
//   ties break toward lower n, matching np.argmin.
__global__ __launch_bounds__(512, 2) void vq_argmin(const float* __restrict__ z,
                                                    const ushort_t* __restrict__ ehi,
                                                    const ushort_t* __restrict__ elo,
                                                    const float* __restrict__ esqs,
                                                    int* __restrict__ cand) {
  __shared__ __align__(16) unsigned char smem[33280]; // 16K ehi + 16K elo + 512B esq
  ushort_t* s_ehi = (ushort_t*)smem;
  ushort_t* s_elo = (ushort_t*)(smem + 16384);
  float*    s_esq = (float*)(smem + 32768);

  const int tid = threadIdx.x;
  const int wave = tid >> 6, lane = tid & 63;
  const int q = lane >> 4, c = lane & 15;
  const int row0 = blockIdx.y * BROWS + wave * 16;
  const int nbase = blockIdx.x * NPB;

  // A fragments (z rows) split hi/lo in-register. A[m=lane&15][k=q*8+j]
  const float* zr = z + (size_t)(row0 + c) * D_DIM;
  float4 a0 = *(const float4*)(zr + q * 8);
  float4 a1 = *(const float4*)(zr + q * 8 + 4);
  float4 a2 = *(const float4*)(zr + 32 + q * 8);
  float4 a3 = *(const float4*)(zr + 32 + q * 8 + 4);
  bf16x8 zh0, zl0, zh1, zl1;
  {
    ushort_t h, l;
    bf16_split(a0.x, h, l); zh0[0] = (short)h; zl0[0] = (short)l;
    bf16_split(a0.y, h, l); zh0[1] = (short)h; zl0[1] = (short)l;
    bf16_split(a0.z, h, l); zh0[2] = (short)h; zl0[2] = (short)l;
    bf16_split(a0.w, h, l); zh0[3] = (short)h; zl0[3] = (short)l;
    bf16_split(a1.x, h, l); zh0[4] = (short)h; zl0[4] = (short)l;
    bf16_split(a1.y, h, l); zh0[5] = (short)h; zl0[5] = (short)l;
    bf16_split(a1.z, h, l); zh0[6] = (short)h; zl0[6] = (short)l;
    bf16_split(a1.w, h, l); zh0[7] = (short)h; zl0[7] = (short)l;
    bf16_split(a2.x, h, l); zh1[0] = (short)h; zl1[0] = (short)l;
    bf16_split(a2.y, h, l); zh1[1] = (short)h; zl1[1] = (short)l;
    bf16_split(a2.z, h, l); zh1[2] = (short)h; zl1[2] = (short)l;
    bf16_split(a2.w, h, l); zh1[3] = (short)h; zl1[3] = (short)l;
    bf16_split(a3.x, h, l); zh1[4] = (short)h; zl1[4] = (short)l;
    bf16_split(a3.y, h, l); zh1[5] = (short)h; zl1[5] = (short)l;
    bf16_split(a3.z, h, l); zh1[6] = (short)h; zl1[6] = (short)l;
    bf16_split(a3.w, h, l); zh1[7] = (short)h; zl1[7] = (short)l;
  }

  // per-(acc row r) top-3 packed-key tracking (12 VGPRs total)
  unsigned K0[4], K1[4], K2[4];
  #pragma unroll
  for (int r = 0; r < 4; ++r) { K0[r] = 0xFFFFFFFFu; K1[r] = 0xFFFFFFFFu; K2[r] = 0xFFFFFFFFu; }

  for (int cb = 0; cb < NPB / BN; ++cb) {
    int nch = nbase + cb * BN;
    __syncthreads();   // previous chunk's LDS reads done
    {
      const uint4* gh = ((const uint4*)ehi) + (size_t)nch * 8;
      const uint4* gl = ((const uint4*)elo) + (size_t)nch * 8;
      uint4 h0 = gh[tid], h1 = gh[tid + 512];
      uint4 l0 = gl[tid], l1 = gl[tid + 512];
      ((uint4*)s_ehi)[tid] = h0; ((uint4*)s_ehi)[tid + 512] = h1;
      ((uint4*)s_elo)[tid] = l0; ((uint4*)s_elo)[tid + 512] = l1;
      if (tid < BN) s_esq[tid] = esqs[nch + tid];
    }
    __syncthreads();

    #pragma unroll
    for (int t = 0; t < BN / 16; ++t) {
      const bf16x8 bh0 = *(const bf16x8*)(s_ehi + t * 1024 + lane * 8);
      const bf16x8 bh1 = *(const bf16x8*)(s_ehi + t * 1024 + 512 + lane * 8);
      const bf16x8 bl0 = *(const bf16x8*)(s_elo + t * 1024 + lane * 8);
      const bf16x8 bl1 = *(const bf16x8*)(s_elo + t * 1024 + 512 + lane * 8);
      f32x4 accA = {0.f, 0.f, 0.f, 0.f}, accB = accA, accC = accA;
      accA = __builtin_amdgcn_mfma_f32_16x16x32_bf16(zh0, bh0, accA, 0, 0, 0);
      accB = __builtin_amdgcn_mfma_f32_16x16x32_bf16(zh0, bl0, accB, 0, 0, 0);
      accC = __builtin_amdgcn_mfma_f32_16x16x32_bf16(zl0, bh0, accC, 0, 0, 0);
      accA = __builtin_amdgcn_mfma_f32_16x16x32_bf16(zh1, bh1, accA, 0, 0, 0);
      accB = __builtin_amdgcn_mfma_f32_16x16x32_bf16(zh1, bl1, accB, 0, 0, 0);
      accC = __builtin_amdgcn_mfma_f32_16x16x32_bf16(zl1, bh1, accC, 0, 0, 0);
      float esqv = s_esq[t * 16 + c];             // pre-scaled by 0.5*2^24
      unsigned n = (unsigned)(nch + t * 16 + c);
      #pragma unroll
      for (int r = 0; r < 4; ++r) {
        float dot = (accA[r] + accB[r]) + accC[r];
        float keyf = fmaf(dot, -SCALE_F, esqv);   // (esq/2 - dot) * 2^24
        int qi = (int)keyf;                       // trunc: weakly monotone
        unsigned pk = (((unsigned)(qi + KBIAS)) << 14) | n;
        bool l0 = pk < K0[r], l1 = pk < K1[r], l2 = pk < K2[r];
        K2[r] = l2 ? (l1 ? K1[r] : pk) : K2[r];
        K1[r] = l1 ? (l0 ? K0[r] : pk) : K1[r];
        K0[r] = l0 ? pk : K0[r];
      }
    }
  }

  // merge 16 lanes' top-3 -> per-row top-4 for this chunk
  __syncthreads();
  unsigned* s_k = (unsigned*)smem;             // [128 rows][16 c][3] = 24 KB
  #pragma unroll
  for (int r = 0; r < 4; ++r) {
    int rowidx = wave * 16 + q * 4 + r;        // C layout: row = q*4 + reg
    int base = (rowidx * 16 + c) * 3;
    s_k[base + 0] = K0[r]; s_k[base + 1] = K1[r]; s_k[base + 2] = K2[r];
  }
  __syncthreads();
  if (tid < BROWS) {
    unsigned M[4] = {0xFFFFFFFFu, 0xFFFFFFFFu, 0xFFFFFFFFu, 0xFFFFFFFFu};
    for (int cc = 0; cc < 48; ++cc) {
      unsigned v = s_k[tid * 48 + cc];
      bool l0 = v < M[0], l1 = v < M[1], l2 = v < M[2], l3 = v < M[3];
      M[3] = l3 ? (l2 ? M[2] : v) : M[3];
      M[2] = l2 ? (l1 ? M[1] : v) : M[2];
      M[1] = l1 ? (l0 ? M[0] : v) : M[1];
      M[0] = l0 ? v : M[0];
    }
    int grow = blockIdx.y * BROWS + tid;
    int* cp = cand + ((size_t)blockIdx.x * L_TOK + grow) * 4;
    cp[0] = (int)(M[0] & 16383u); cp[1] = (int)(M[1] & 16383u);
    cp[2] = (int)(M[2] & 16383u); cp[3] = (int)(M[3] & 16383u);
  }
}

// ------- kernel 3: np-fp32-exact rescore of 16 candidates, outputs ----------
// grid = L/128, block = 512 (8 waves, 16 row-iters)
__global__ __launch_bounds__(512, 2) void vq_refine(const float* __restrict__ z,
                                                    const float* __restrict__ e,
                                                    const float* __restrict__ esqg,
                                                    const int* __restrict__ cand,
                                                    float* __restrict__ out,
                                                    double* __restrict__ partials) {
  const int tid = threadIdx.x;
  const int wave = tid >> 6, lane = tid & 63;
  __shared__ double sp[8];
  double wl = 0.0;
  for (int it = 0; it < 16; ++it) {
    int row = blockIdx.x * 128 + it * 8 + wave;
    float zf = z[(size_t)row * D_DIM + lane];
    float zsq = np_sum64(zf * zf);             // numpy-bit-exact sum(z*z, axis=1)
    float bestd = 3.4e38f; int bi = 0x7fffffff; float be = 0.f;
    #pragma unroll
    for (int cc = 0; cc < 16; ++cc) {
      int idx = cand[((size_t)(cc >> 2) * L_TOK + row) * 4 + (cc & 3)];
      float ef = e[(size_t)idx * D_DIM + lane];
      double p = (double)zf * (double)ef;
      #pragma unroll
      for (int o = 32; o; o >>= 1) p += __shfl_xor(p, o);
      // emulate np fp32: d = fl32( fl32(zsq + esq) - fl32(2*dot) )
      float t2 = (float)(2.0 * p);
      float T1 = zsq + esqg[idx];
      float d = T1 - t2;
      bool better = (d < bestd) || (d == bestd && idx < bi);  // first-min tie-break
      if (better) { bestd = d; bi = idx; be = ef; }
    }
    // straight-through output, fp32 op order: z + (z_q - z)
    out[(size_t)row * D_DIM + lane] = zf + (be - zf);
    if (lane == 0) out[(size_t)L_TOK * D_DIM + 1 + row] = (float)bi;
    // loss term in fp64 (threshold is loose)
    double df = (double)be - (double)zf;
    double s = df * df;
    #pragma unroll
    for (int o = 32; o; o >>= 1) s += __shfl_xor(s, o);
    wl += s;
  }
  if (lane == 0) sp[wave] = wl;
  __syncthreads();
  if (tid == 0) {
    double t = 0.0;
    #pragma unroll
    for (int w = 0; w < 8; ++w) t += sp[w];
    partials[blockIdx.x] = t;
  }
}

// ---------------- kernel 4: finalize loss ------------------------------------
__global__ __launch_bounds__(256) void vq_loss(const double* __restrict__ partials,
                                               float* __restrict__ out) {
  int tid = threadIdx.x;
  double v = partials[tid];
  #pragma unroll
  for (int o = 32; o; o >>= 1) v += __shfl_xor(v, o);
  __shared__ double sp[4];
  if ((tid & 63) == 0) sp[tid >> 6] = v;
  __syncthreads();
  if (tid == 0) {
    double tot = sp[0] + sp[1] + sp[2] + sp[3];
    // loss = beta*mean + mean = 1.25 * mean((z_q - z)^2)
    out[(size_t)L_TOK * D_DIM] = (float)(1.25 * tot / (double)((size_t)L_TOK * D_DIM));
  }
}

extern "C" void kernel_launch(void* const* d_in, const int* in_sizes, int n_in,
                              void* d_out, int out_size, void* d_ws, size_t ws_size,
                              hipStream_t stream) {
  const float* z = (const float*)d_in[0];       // (32768, 64) fp32
  const float* e = (const float*)d_in[1];       // (16384, 64) fp32
  float* out = (float*)d_out;                   // [z_q_st | loss | indices-as-f32]
  char* ws = (char*)d_ws;                       // needs ~6.3 MB

  ushort_t* ehi   = (ushort_t*)(ws + WS_EHI);
  ushort_t* elo   = (ushort_t*)(ws + WS_ELO);
  float*    esqg  = (float*)(ws + WS_ESQ);
  float*    esqs  = (float*)(ws + WS_ESQS);
  int*      cand  = (int*)(ws + WS_CAND);
  double*   parts = (double*)(ws + WS_PART);

  vq_prep_e<<<NE / 4, 256, 0, stream>>>(e, ehi, elo, esqg, esqs);
  vq_argmin<<<dim3(GCHUNKS, L_TOK / BROWS), 512, 0, stream>>>(z, ehi, elo, esqs, cand);
  vq_refine<<<L_TOK / 128, 512, 0, stream>>>(z, e, esqg, cand, out, parts);
  vq_loss<<<1, 256, 0, stream>>>(parts, out);
}

// Round 4
// 331.928 us; speedup vs baseline: 11.1714x; 1.6932x over previous
//
#include <hip/hip_runtime.h>
#include <cstdint>
#include <cstddef>

// Problem constants (VectorQuantizer: L=32768, D=64, N_E=16384, beta=0.25)
#define L_TOK 32768
#define D_DIM 64
#define NE    16384
#define GCHUNKS 4              // N split across grid
#define NPB   (NE / GCHUNKS)   // 4096 n per block
#define BN    128              // n per LDS stage chunk
#define BROWS 128              // rows per block (8 waves x 16)

#define SCALE_F 16777216.0f    // 2^24 (exact fp32 scaling)
#define KBIAS_F 131072.0f      // 2^17, folded into esqs at prep

typedef unsigned short ushort_t;
typedef __attribute__((ext_vector_type(8))) short bf16x8;
typedef __attribute__((ext_vector_type(4))) float f32x4;

// ---- ws layout (bytes) ----
#define WS_EHI   0u                                  // 2 MB   e_hi permuted
#define WS_ELO   (2u<<20)                            // 2 MB   e_lo permuted
#define WS_ESQ32 (4u<<20)                            // 64 KB  esq np-exact fp32
#define WS_ESQS  ((4u<<20) + (64u<<10))              // 64 KB  esq*0.5*2^24 + 2^17
#define WS_ESQ64 ((4u<<20) + (128u<<10))             // 128 KB esq fp64 (loss)
#define WS_ZSQ32 ((4u<<20) + (256u<<10))             // 128 KB zsq np-exact fp32
#define WS_ZSQ64 ((4u<<20) + (384u<<10))             // 256 KB zsq fp64 (loss)
#define WS_CAND  ((4u<<20) + (640u<<10))             // 2 MB   cand[4][L][4] int
#define WS_PART  ((6u<<20) + (640u<<10))             // 4 KB   loss partials (512 dbl)

__device__ __forceinline__ void bf16_split(float v, ushort_t& hs, ushort_t& ls) {
  unsigned u  = __float_as_uint(v);
  unsigned ur = u + 0x7fffu + ((u >> 16) & 1u);      // RNE to bf16
  hs = (ushort_t)(ur >> 16);
  float hf = __uint_as_float(ur & 0xffff0000u);
  float r  = v - hf;                                  // exact residual
  unsigned u2  = __float_as_uint(r);
  unsigned ur2 = u2 + 0x7fffu + ((u2 >> 16) & 1u);
  ls = (ushort_t)(ur2 >> 16);
}

// numpy pairwise_sum emulation for n=64 contiguous fp32 (scalar 8-acc path).
__device__ __forceinline__ float np_sum64(float a) {
  int j = threadIdx.x & 7;
  float r = __shfl(a, j);
  #pragma unroll
  for (int m = 1; m < 8; ++m) r += __shfl(a, j + 8 * m);
  float s0 = __shfl(r, 0), s1 = __shfl(r, 1), s2 = __shfl(r, 2), s3 = __shfl(r, 3);
  float s4 = __shfl(r, 4), s5 = __shfl(r, 5), s6 = __shfl(r, 6), s7 = __shfl(r, 7);
  return ((s0 + s1) + (s2 + s3)) + ((s4 + s5) + (s6 + s7));
}

// Fragment-permuted index (in ushorts) for element (n, k) — LDS staging order
// equals MFMA B-fragment consumption order (conflict-free ds_read_b128).
__device__ __forceinline__ int perm_off(int n, int k) {
  int tile = n >> 4, c = n & 15, s = k >> 5, q = (k >> 3) & 3, j = k & 7;
  return tile * 1024 + s * 512 + (q * 16 + c) * 8 + j;
}

// ---------------- kernel 1: prep embedding -----------------------------------
__global__ __launch_bounds__(256) void vq_prep_e(const float* __restrict__ e,
                                                 ushort_t* __restrict__ ehi,
                                                 ushort_t* __restrict__ elo,
                                                 float* __restrict__ esq32,
                                                 float* __restrict__ esqs,
                                                 double* __restrict__ esq64) {
  int wave = threadIdx.x >> 6, lane = threadIdx.x & 63;
  int row = blockIdx.x * 4 + wave;            // one wave per embedding row
  float v = e[(size_t)row * D_DIM + lane];
  ushort_t hs, ls;
  bf16_split(v, hs, ls);
  int off = perm_off(row, lane);
  ehi[off] = hs;
  elo[off] = ls;
  float esq = np_sum64(v * v);                // numpy-bit-exact sum(e*e, axis=1)
  double p = (double)v * (double)v;
  #pragma unroll
  for (int o = 32; o; o >>= 1) p += __shfl_xor(p, o);
  if (lane == 0) {
    esq32[row] = esq;                                  // exact rescore
    esqs[row]  = (esq * 0.5f) * SCALE_F + KBIAS_F;     // pre-biased sieve constant
    esq64[row] = p;                                    // loss
  }
}

// ---------------- kernel 1b: prep z row sums ---------------------------------
__global__ __launch_bounds__(256) void vq_prep_z(const float* __restrict__ z,
                                                 float* __restrict__ zsq32,
                                                 double* __restrict__ zsq64) {
  int wave = threadIdx.x >> 6, lane = threadIdx.x & 63;
  int row = blockIdx.x * 4 + wave;
  float v = z[(size_t)row * D_DIM + lane];
  float s32 = np_sum64(v * v);                // numpy-bit-exact sum(z*z, axis=1)
  double p = (double)v * (double)v;
  #pragma unroll
  for (int o = 32; o; o >>= 1) p += __shfl_xor(p, o);
  if (lane == 0) { zsq32[row] = s32; zsq64[row] = p; }
}

// ---------------- kernel 2: fused distance + per-row top-k sieve -------------
// grid = dim3(GCHUNKS, L/BROWS), block = 512 (8 waves x 16 rows each)
// Packed sort-key: (trunc((esq/2 - dot)*2^24 + 2^17) << 14) | n  — positive by
// Cauchy-Schwarz (|dot|*2^24 < 9.1e4 < 2^17); weakly monotone in d with
// 6e-8 buckets << the 7.6e-6 np-fp32 window the refine net resolves;
// ties break toward lower n, matching np.argmin.
__global__ __launch_bounds__(512, 4) void vq_argmin(const float* __restrict__ z,
                                                    const ushort_t* __restrict__ ehi,
                                                    const ushort_t* __restrict__ elo,
                                                    const float* __restrict__ esqs,
                                                    int* __restrict__ cand) {
  __shared__ __align__(16) unsigned char smem[33280]; // 16K ehi + 16K elo + 512B esq
  ushort_t* s_ehi = (ushort_t*)smem;
  ushort_t* s_elo = (ushort_t*)(smem + 16384);
  float*    s_esq = (float*)(smem + 32768);

  const int tid = threadIdx.x;
  const int wave = tid >> 6, lane = tid & 63;
  const int q = lane >> 4, c = lane & 15;
  const int row0 = blockIdx.y * BROWS + wave * 16;
  const int nbase = blockIdx.x * NPB;

  // A fragments (z rows) split hi/lo in-register. A[m=lane&15][k=q*8+j]
  const float* zr = z + (size_t)(row0 + c) * D_DIM;
  float4 a0 = *(const float4*)(zr + q * 8);
  float4 a1 = *(const float4*)(zr + q * 8 + 4);
  float4 a2 = *(const float4*)(zr + 32 + q * 8);
  float4 a3 = *(const float4*)(zr + 32 + q * 8 + 4);
  bf16x8 zh0, zl0, zh1, zl1;
  {
    ushort_t h, l;
    bf16_split(a0.x, h, l); zh0[0] = (short)h; zl0[0] = (short)l;
    bf16_split(a0.y, h, l); zh0[1] = (short)h; zl0[1] = (short)l;
    bf16_split(a0.z, h, l); zh0[2] = (short)h; zl0[2] = (short)l;
    bf16_split(a0.w, h, l); zh0[3] = (short)h; zl0[3] = (short)l;
    bf16_split(a1.x, h, l); zh0[4] = (short)h; zl0[4] = (short)l;
    bf16_split(a1.y, h, l); zh0[5] = (short)h; zl0[5] = (short)l;
    bf16_split(a1.z, h, l); zh0[6] = (short)h; zl0[6] = (short)l;
    bf16_split(a1.w, h, l); zh0[7] = (short)h; zl0[7] = (short)l;
    bf16_split(a2.x, h, l); zh1[0] = (short)h; zl1[0] = (short)l;
    bf16_split(a2.y, h, l); zh1[1] = (short)h; zl1[1] = (short)l;
    bf16_split(a2.z, h, l); zh1[2] = (short)h; zl1[2] = (short)l;
    bf16_split(a2.w, h, l); zh1[3] = (short)h; zl1[3] = (short)l;
    bf16_split(a3.x, h, l); zh1[4] = (short)h; zl1[4] = (short)l;
    bf16_split(a3.y, h, l); zh1[5] = (short)h; zl1[5] = (short)l;
    bf16_split(a3.z, h, l); zh1[6] = (short)h; zl1[6] = (short)l;
    bf16_split(a3.w, h, l); zh1[7] = (short)h; zl1[7] = (short)l;
  }

  // per-(acc row r) top-3 packed-key tracking (12 VGPRs)
  unsigned K0[4], K1[4], K2[4];
  #pragma unroll
  for (int r = 0; r < 4; ++r) { K0[r] = 0xFFFFFFFFu; K1[r] = 0xFFFFFFFFu; K2[r] = 0xFFFFFFFFu; }

  for (int cb = 0; cb < NPB / BN; ++cb) {
    int nch = nbase + cb * BN;
    __syncthreads();   // previous chunk's LDS reads done
    {
      const uint4* gh = ((const uint4*)ehi) + (size_t)nch * 8;
      const uint4* gl = ((const uint4*)elo) + (size_t)nch * 8;
      uint4 h0 = gh[tid], h1 = gh[tid + 512];
      uint4 l0 = gl[tid], l1 = gl[tid + 512];
      ((uint4*)s_ehi)[tid] = h0; ((uint4*)s_ehi)[tid + 512] = h1;
      ((uint4*)s_elo)[tid] = l0; ((uint4*)s_elo)[tid + 512] = l1;
      if (tid < BN) s_esq[tid] = esqs[nch + tid];
    }
    __syncthreads();

    #pragma unroll 2
    for (int t = 0; t < BN / 16; ++t) {
      const bf16x8 bh0 = *(const bf16x8*)(s_ehi + t * 1024 + lane * 8);
      const bf16x8 bh1 = *(const bf16x8*)(s_ehi + t * 1024 + 512 + lane * 8);
      const bf16x8 bl0 = *(const bf16x8*)(s_elo + t * 1024 + lane * 8);
      const bf16x8 bl1 = *(const bf16x8*)(s_elo + t * 1024 + 512 + lane * 8);
      // single fp32 accumulator chain: hi*hi + hi*lo + lo*hi (chain err ~1e-9)
      f32x4 acc = {0.f, 0.f, 0.f, 0.f};
      acc = __builtin_amdgcn_mfma_f32_16x16x32_bf16(zh0, bh0, acc, 0, 0, 0);
      acc = __builtin_amdgcn_mfma_f32_16x16x32_bf16(zh0, bl0, acc, 0, 0, 0);
      acc = __builtin_amdgcn_mfma_f32_16x16x32_bf16(zl0, bh0, acc, 0, 0, 0);
      acc = __builtin_amdgcn_mfma_f32_16x16x32_bf16(zh1, bh1, acc, 0, 0, 0);
      acc = __builtin_amdgcn_mfma_f32_16x16x32_bf16(zh1, bl1, acc, 0, 0, 0);
      acc = __builtin_amdgcn_mfma_f32_16x16x32_bf16(zl1, bh1, acc, 0, 0, 0);
      float esqv = s_esq[t * 16 + c];             // pre-scaled + pre-biased
      unsigned nv = (unsigned)(nch + t * 16 + c);
      #pragma unroll
      for (int r = 0; r < 4; ++r) {
        unsigned qi = (unsigned)fmaf(acc[r], -SCALE_F, esqv);  // trunc, positive
        unsigned pk = (qi << 14) | nv;
        // top-3 via min/max chain (fuses to v_med3_u32)
        K2[r] = min(max(pk, K1[r]), K2[r]);
        K1[r] = min(max(pk, K0[r]), K1[r]);
        K0[r] = min(pk, K0[r]);
      }
    }
  }

  // merge 16 lanes' top-3 -> per-row top-4 for this chunk
  __syncthreads();
  unsigned* s_k = (unsigned*)smem;             // [128 rows][16 c][3] = 24 KB
  #pragma unroll
  for (int r = 0; r < 4; ++r) {
    int rowidx = wave * 16 + q * 4 + r;        // C layout: row = q*4 + reg
    int base = (rowidx * 16 + c) * 3;
    s_k[base + 0] = K0[r]; s_k[base + 1] = K1[r]; s_k[base + 2] = K2[r];
  }
  __syncthreads();
  if (tid < BROWS) {
    unsigned M0 = 0xFFFFFFFFu, M1 = 0xFFFFFFFFu, M2 = 0xFFFFFFFFu, M3 = 0xFFFFFFFFu;
    const uint4* sv = (const uint4*)(s_k + tid * 48);
    #pragma unroll
    for (int v4 = 0; v4 < 12; ++v4) {
      uint4 kk = sv[v4];
      unsigned vals[4] = {kk.x, kk.y, kk.z, kk.w};
      #pragma unroll
      for (int u = 0; u < 4; ++u) {
        unsigned v = vals[u];
        M3 = min(max(v, M2), M3);
        M2 = min(max(v, M1), M2);
        M1 = min(max(v, M0), M1);
        M0 = min(v, M0);
      }
    }
    int grow = blockIdx.y * BROWS + tid;
    int* cp = cand + ((size_t)blockIdx.x * L_TOK + grow) * 4;
    cp[0] = (int)(M0 & 16383u); cp[1] = (int)(M1 & 16383u);
    cp[2] = (int)(M2 & 16383u); cp[3] = (int)(M3 & 16383u);
  }
}

// ------- kernel 3: np-fp32-exact rescore of 16 candidates, outputs ----------
// grid = L/64 blocks, block 512 (8 waves); each wave: 8 rows, 4 lanes/candidate.
__global__ __launch_bounds__(512, 4) void vq_refine(const float* __restrict__ z,
                                                    const float* __restrict__ e,
                                                    const float* __restrict__ esq32,
                                                    const double* __restrict__ esq64,
                                                    const float* __restrict__ zsq32,
                                                    const double* __restrict__ zsq64,
                                                    const int* __restrict__ cand,
                                                    float* __restrict__ out,
                                                    double* __restrict__ partials) {
  const int tid = threadIdx.x;
  const int wave = tid >> 6, lane = tid & 63;
  const int g = lane >> 2, s = lane & 3;      // 16 cand-groups x 4 lanes
  __shared__ double sp[8];
  double wl = 0.0;
  for (int it = 0; it < 8; ++it) {
    int row = blockIdx.x * 64 + wave * 8 + it;
    int idx = cand[((size_t)(g >> 2) * L_TOK + row) * 4 + (g & 3)];
    // fp64 dot over 16 elements/lane, then 2-step in-group reduce
    const float4* ep = (const float4*)(e + (size_t)idx * D_DIM + s * 16);
    const float4* zp = (const float4*)(z + (size_t)row * D_DIM + s * 16);
    double dot = 0.0;
    #pragma unroll
    for (int j = 0; j < 4; ++j) {
      float4 ev = ep[j], zv = zp[j];
      dot = fma((double)ev.x, (double)zv.x, dot);
      dot = fma((double)ev.y, (double)zv.y, dot);
      dot = fma((double)ev.z, (double)zv.z, dot);
      dot = fma((double)ev.w, (double)zv.w, dot);
    }
    dot += __shfl_xor(dot, 1);
    dot += __shfl_xor(dot, 2);
    // emulate np fp32: d = fl32( fl32(zsq + esq) - fl32(2*dot) )
    float t2 = (float)(2.0 * dot);
    float T1 = zsq32[row] + esq32[idx];
    float d  = T1 - t2;                        // d ~ 64 > 0: bits are monotone
    unsigned long long key = ((unsigned long long)__float_as_uint(d) << 14)
                           | (unsigned)idx;    // tie -> lower idx (np.argmin)
    double dotw = dot;
    #pragma unroll
    for (int o = 4; o <= 32; o <<= 1) {
      unsigned long long ok = __shfl_xor(key, o);
      double od = __shfl_xor(dotw, o);
      bool take = ok < key;
      key  = take ? ok : key;
      dotw = take ? od : dotw;
    }
    int win = (int)(key & 16383u);
    // outputs (element layout; whole wave)
    float zf = z[(size_t)row * D_DIM + lane];
    float be = e[(size_t)win * D_DIM + lane];
    out[(size_t)row * D_DIM + lane] = zf + (be - zf);   // fp32 op-order ST
    if (lane == 0) {
      out[(size_t)L_TOK * D_DIM + 1 + row] = (float)win;
      wl += zsq64[row] + esq64[win] - 2.0 * dotw;       // ||z - e_win||^2 (fp64)
    }
  }
  if (lane == 0) sp[wave] = wl;
  __syncthreads();
  if (tid == 0) {
    double t = 0.0;
    #pragma unroll
    for (int w = 0; w < 8; ++w) t += sp[w];
    partials[blockIdx.x] = t;
  }
}

// ---------------- kernel 4: finalize loss (512 partials) ---------------------
__global__ __launch_bounds__(512) void vq_loss(const double* __restrict__ partials,
                                               float* __restrict__ out) {
  int tid = threadIdx.x;
  double v = partials[tid];
  #pragma unroll
  for (int o = 32; o; o >>= 1) v += __shfl_xor(v, o);
  __shared__ double sp[8];
  if ((tid & 63) == 0) sp[tid >> 6] = v;
  __syncthreads();
  if (tid == 0) {
    double tot = 0.0;
    #pragma unroll
    for (int w = 0; w < 8; ++w) tot += sp[w];
    // loss = beta*mean + mean = 1.25 * mean((z_q - z)^2)
    out[(size_t)L_TOK * D_DIM] = (float)(1.25 * tot / (double)((size_t)L_TOK * D_DIM));
  }
}

extern "C" void kernel_launch(void* const* d_in, const int* in_sizes, int n_in,
                              void* d_out, int out_size, void* d_ws, size_t ws_size,
                              hipStream_t stream) {
  const float* z = (const float*)d_in[0];       // (32768, 64) fp32
  const float* e = (const float*)d_in[1];       // (16384, 64) fp32
  float* out = (float*)d_out;                   // [z_q_st | loss | indices-as-f32]
  char* ws = (char*)d_ws;                       // needs ~6.8 MB

  ushort_t* ehi   = (ushort_t*)(ws + WS_EHI);
  ushort_t* elo   = (ushort_t*)(ws + WS_ELO);
  float*    esq32 = (float*)(ws + WS_ESQ32);
  float*    esqs  = (float*)(ws + WS_ESQS);
  double*   esq64 = (double*)(ws + WS_ESQ64);
  float*    zsq32 = (float*)(ws + WS_ZSQ32);
  double*   zsq64 = (double*)(ws + WS_ZSQ64);
  int*      cand  = (int*)(ws + WS_CAND);
  double*   parts = (double*)(ws + WS_PART);

  vq_prep_e<<<NE / 4, 256, 0, stream>>>(e, ehi, elo, esq32, esqs, esq64);
  vq_prep_z<<<L_TOK / 4, 256, 0, stream>>>(z, zsq32, zsq64);
  vq_argmin<<<dim3(GCHUNKS, L_TOK / BROWS), 512, 0, stream>>>(z, ehi, elo, esqs, cand);
  vq_refine<<<L_TOK / 64, 512, 0, stream>>>(z, e, esq32, esq64, zsq32, zsq64,
                                            cand, out, parts);
  vq_loss<<<1, 512, 0, stream>>>(parts, out);
}

// Round 5
// 266.280 us; speedup vs baseline: 13.9256x; 1.2465x over previous
//
#include <hip/hip_runtime.h>
#include <cstdint>
#include <cstddef>

// Problem constants (VectorQuantizer: L=32768, D=64, N_E=16384, beta=0.25)
#define L_TOK 32768
#define D_DIM 64
#define NE    16384
#define GCHUNKS 4              // N split across grid
#define NPB   (NE / GCHUNKS)   // 4096 n per block
#define BN    256              // n per LDS stage chunk
#define BROWS 128              // rows per block (8 waves x 16)

#define SCALE_F 16777216.0f    // 2^24 (exact fp32 scaling)
#define KBIAS_F 131072.0f      // 2^17, folded into esqs at prep

typedef unsigned short ushort_t;
typedef __attribute__((ext_vector_type(8))) short bf16x8;
typedef __attribute__((ext_vector_type(4))) float f32x4;

// ---- ws layout (bytes) ----
#define WS_EHI   0u                                  // 2 MB   e bf16(RNE) permuted
#define WS_ESQ32 (2u<<20)                            // 64 KB  esq np-exact fp32
#define WS_ESQS  ((2u<<20) + (64u<<10))              // 64 KB  esq*0.5*2^24 + 2^17
#define WS_ESQ64 ((2u<<20) + (128u<<10))             // 128 KB esq fp64 (loss)
#define WS_ZSQ32 ((2u<<20) + (256u<<10))             // 128 KB zsq np-exact fp32
#define WS_ZSQ64 ((2u<<20) + (384u<<10))             // 256 KB zsq fp64 (loss)
#define WS_CAND  ((2u<<20) + (640u<<10))             // 2 MB   cand[4][L][4] int
#define WS_PART  ((4u<<20) + (640u<<10))             // 8 KB   loss partials (1024 dbl)

__device__ __forceinline__ ushort_t bf16_rne(float v) {
  unsigned u = __float_as_uint(v);
  return (ushort_t)((u + 0x7fffu + ((u >> 16) & 1u)) >> 16);
}

// numpy pairwise_sum emulation for n=64 contiguous fp32 (scalar 8-acc path).
__device__ __forceinline__ float np_sum64(float a) {
  int j = threadIdx.x & 7;
  float r = __shfl(a, j);
  #pragma unroll
  for (int m = 1; m < 8; ++m) r += __shfl(a, j + 8 * m);
  float s0 = __shfl(r, 0), s1 = __shfl(r, 1), s2 = __shfl(r, 2), s3 = __shfl(r, 3);
  float s4 = __shfl(r, 4), s5 = __shfl(r, 5), s6 = __shfl(r, 6), s7 = __shfl(r, 7);
  return ((s0 + s1) + (s2 + s3)) + ((s4 + s5) + (s6 + s7));
}

// Fragment-permuted index (in ushorts) for element (n, k) — LDS staging order
// equals MFMA B-fragment consumption order (conflict-free ds_read_b128).
__device__ __forceinline__ int perm_off(int n, int k) {
  int tile = n >> 4, c = n & 15, s = k >> 5, q = (k >> 3) & 3, j = k & 7;
  return tile * 1024 + s * 512 + (q * 16 + c) * 8 + j;
}

// ---------------- kernel 1: prep embedding -----------------------------------
__global__ __launch_bounds__(256) void vq_prep_e(const float* __restrict__ e,
                                                 ushort_t* __restrict__ ehi,
                                                 float* __restrict__ esq32,
                                                 float* __restrict__ esqs,
                                                 double* __restrict__ esq64) {
  int wave = threadIdx.x >> 6, lane = threadIdx.x & 63;
  int row = blockIdx.x * 4 + wave;            // one wave per embedding row
  float v = e[(size_t)row * D_DIM + lane];
  ehi[perm_off(row, lane)] = bf16_rne(v);
  float esq = np_sum64(v * v);                // numpy-bit-exact sum(e*e, axis=1)
  double p = (double)v * (double)v;
  #pragma unroll
  for (int o = 32; o; o >>= 1) p += __shfl_xor(p, o);
  if (lane == 0) {
    esq32[row] = esq;                                  // exact rescore
    esqs[row]  = (esq * 0.5f) * SCALE_F + KBIAS_F;     // pre-biased sieve constant
    esq64[row] = p;                                    // loss
  }
}

// ---------------- kernel 1b: prep z row sums ---------------------------------
__global__ __launch_bounds__(256) void vq_prep_z(const float* __restrict__ z,
                                                 float* __restrict__ zsq32,
                                                 double* __restrict__ zsq64) {
  int wave = threadIdx.x >> 6, lane = threadIdx.x & 63;
  int row = blockIdx.x * 4 + wave;
  float v = z[(size_t)row * D_DIM + lane];
  float s32 = np_sum64(v * v);                // numpy-bit-exact sum(z*z, axis=1)
  double p = (double)v * (double)v;
  #pragma unroll
  for (int o = 32; o; o >>= 1) p += __shfl_xor(p, o);
  if (lane == 0) { zsq32[row] = s32; zsq64[row] = p; }
}

// ---------------- kernel 2: fused distance + per-row top-k sieve -------------
// grid = dim3(GCHUNKS, L/BROWS), block = 512 (8 waves x 16 rows each)
// Pure-bf16 sieve (sigma ~4.3e-7 noise << 7.6e-6 np-fp32 quantization window
// already absorbed by top-4/chunk + exact rescore).  Packed sort-key:
// (trunc((esq/2 - dot)*2^24 + 2^17) << 14) | n  — positive by Cauchy-Schwarz
// (|dot|*2^24 < 9e4 < 2^17); ties break toward lower n, matching np.argmin.
__global__ __launch_bounds__(512, 4) void vq_argmin(const float* __restrict__ z,
                                                    const ushort_t* __restrict__ ehi,
                                                    const float* __restrict__ esqs,
                                                    int* __restrict__ cand) {
  __shared__ __align__(16) unsigned char smem[33792]; // 32K ehi + 1K esq
  ushort_t* s_ehi = (ushort_t*)smem;
  float*    s_esq = (float*)(smem + 32768);

  const int tid = threadIdx.x;
  const int wave = tid >> 6, lane = tid & 63;
  const int q = lane >> 4, c = lane & 15;
  const int row0 = blockIdx.y * BROWS + wave * 16;
  const int nbase = blockIdx.x * NPB;

  // A fragments (z rows) rounded to bf16 in-register. A[m=lane&15][k=q*8+j]
  const float* zr = z + (size_t)(row0 + c) * D_DIM;
  float4 a0 = *(const float4*)(zr + q * 8);
  float4 a1 = *(const float4*)(zr + q * 8 + 4);
  float4 a2 = *(const float4*)(zr + 32 + q * 8);
  float4 a3 = *(const float4*)(zr + 32 + q * 8 + 4);
  bf16x8 zh0, zh1;
  zh0[0] = (short)bf16_rne(a0.x); zh0[1] = (short)bf16_rne(a0.y);
  zh0[2] = (short)bf16_rne(a0.z); zh0[3] = (short)bf16_rne(a0.w);
  zh0[4] = (short)bf16_rne(a1.x); zh0[5] = (short)bf16_rne(a1.y);
  zh0[6] = (short)bf16_rne(a1.z); zh0[7] = (short)bf16_rne(a1.w);
  zh1[0] = (short)bf16_rne(a2.x); zh1[1] = (short)bf16_rne(a2.y);
  zh1[2] = (short)bf16_rne(a2.z); zh1[3] = (short)bf16_rne(a2.w);
  zh1[4] = (short)bf16_rne(a3.x); zh1[5] = (short)bf16_rne(a3.y);
  zh1[6] = (short)bf16_rne(a3.z); zh1[7] = (short)bf16_rne(a3.w);

  const f32x4 fzero = {0.f, 0.f, 0.f, 0.f};  // persistent zero C operand

  // per-(acc row r) top-3 packed-key tracking (12 VGPRs)
  unsigned K0[4], K1[4], K2[4];
  #pragma unroll
  for (int r = 0; r < 4; ++r) { K0[r] = 0xFFFFFFFFu; K1[r] = 0xFFFFFFFFu; K2[r] = 0xFFFFFFFFu; }

  for (int cb = 0; cb < NPB / BN; ++cb) {
    int nch = nbase + cb * BN;
    __syncthreads();   // previous chunk's LDS reads done
    {
      const uint4* gh = ((const uint4*)ehi) + (size_t)nch * 8;  // 8 uint4 per n
      uint4* sb = (uint4*)s_ehi;
      uint4 v0 = gh[tid], v1 = gh[tid + 512], v2 = gh[tid + 1024], v3 = gh[tid + 1536];
      sb[tid] = v0; sb[tid + 512] = v1; sb[tid + 1024] = v2; sb[tid + 1536] = v3;
      if (tid < BN) s_esq[tid] = esqs[nch + tid];
    }
    __syncthreads();

    #pragma unroll 4
    for (int t = 0; t < BN / 16; ++t) {
      const bf16x8 bh0 = *(const bf16x8*)(s_ehi + t * 1024 + lane * 8);
      const bf16x8 bh1 = *(const bf16x8*)(s_ehi + t * 1024 + 512 + lane * 8);
      f32x4 acc = __builtin_amdgcn_mfma_f32_16x16x32_bf16(zh0, bh0, fzero, 0, 0, 0);
      acc = __builtin_amdgcn_mfma_f32_16x16x32_bf16(zh1, bh1, acc, 0, 0, 0);
      float esqv = s_esq[t * 16 + c];             // pre-scaled + pre-biased
      unsigned nv = (unsigned)(nch + t * 16 + c);
      #pragma unroll
      for (int r = 0; r < 4; ++r) {
        unsigned qi = (unsigned)fmaf(acc[r], -SCALE_F, esqv);  // trunc, positive
        unsigned pk = (qi << 14) | nv;
        K2[r] = min(max(pk, K1[r]), K2[r]);       // top-3 via med3-fusable chain
        K1[r] = min(max(pk, K0[r]), K1[r]);
        K0[r] = min(pk, K0[r]);
      }
    }
  }

  // merge 16 lanes' top-3 -> per-row top-4 for this chunk
  __syncthreads();
  unsigned* s_k = (unsigned*)smem;             // [128 rows][16 c][3] = 24 KB
  #pragma unroll
  for (int r = 0; r < 4; ++r) {
    int rowidx = wave * 16 + q * 4 + r;        // C layout: row = q*4 + reg
    int base = (rowidx * 16 + c) * 3;
    s_k[base + 0] = K0[r]; s_k[base + 1] = K1[r]; s_k[base + 2] = K2[r];
  }
  __syncthreads();
  if (tid < BROWS) {
    unsigned M0 = 0xFFFFFFFFu, M1 = 0xFFFFFFFFu, M2 = 0xFFFFFFFFu, M3 = 0xFFFFFFFFu;
    const uint4* sv = (const uint4*)(s_k + tid * 48);
    #pragma unroll
    for (int v4 = 0; v4 < 12; ++v4) {
      uint4 kk = sv[v4];
      unsigned vals[4] = {kk.x, kk.y, kk.z, kk.w};
      #pragma unroll
      for (int u = 0; u < 4; ++u) {
        unsigned v = vals[u];
        M3 = min(max(v, M2), M3);
        M2 = min(max(v, M1), M2);
        M1 = min(max(v, M0), M1);
        M0 = min(v, M0);
      }
    }
    int grow = blockIdx.y * BROWS + tid;
    int* cp = cand + ((size_t)blockIdx.x * L_TOK + grow) * 4;
    cp[0] = (int)(M0 & 16383u); cp[1] = (int)(M1 & 16383u);
    cp[2] = (int)(M2 & 16383u); cp[3] = (int)(M3 & 16383u);
  }
}

// ------- kernel 3: np-fp32-exact rescore of 16 candidates, outputs ----------
// grid = L/32 blocks, block 512 (8 waves); each wave: 4 rows, 4 lanes/candidate.
__global__ __launch_bounds__(512, 4) void vq_refine(const float* __restrict__ z,
                                                    const float* __restrict__ e,
                                                    const float* __restrict__ esq32,
                                                    const double* __restrict__ esq64,
                                                    const float* __restrict__ zsq32,
                                                    const double* __restrict__ zsq64,
                                                    const int* __restrict__ cand,
                                                    float* __restrict__ out,
                                                    double* __restrict__ partials) {
  const int tid = threadIdx.x;
  const int wave = tid >> 6, lane = tid & 63;
  const int g = lane >> 2, s = lane & 3;      // 16 cand-groups x 4 lanes
  __shared__ double sp[8];
  double wl = 0.0;
  for (int it = 0; it < 4; ++it) {
    int row = blockIdx.x * 32 + wave * 4 + it;
    int idx = cand[((size_t)(g >> 2) * L_TOK + row) * 4 + (g & 3)];
    // fp64 dot over 16 elements/lane, then 2-step in-group reduce
    const float4* ep = (const float4*)(e + (size_t)idx * D_DIM + s * 16);
    const float4* zp = (const float4*)(z + (size_t)row * D_DIM + s * 16);
    double dot = 0.0;
    #pragma unroll
    for (int j = 0; j < 4; ++j) {
      float4 ev = ep[j], zv = zp[j];
      dot = fma((double)ev.x, (double)zv.x, dot);
      dot = fma((double)ev.y, (double)zv.y, dot);
      dot = fma((double)ev.z, (double)zv.z, dot);
      dot = fma((double)ev.w, (double)zv.w, dot);
    }
    dot += __shfl_xor(dot, 1);
    dot += __shfl_xor(dot, 2);
    // emulate np fp32: d = fl32( fl32(zsq + esq) - fl32(2*dot) )
    float t2 = (float)(2.0 * dot);
    float T1 = zsq32[row] + esq32[idx];
    float d  = T1 - t2;                        // d ~ 64 > 0: bits are monotone
    unsigned long long key = ((unsigned long long)__float_as_uint(d) << 14)
                           | (unsigned)idx;    // tie -> lower idx (np.argmin)
    double dotw = dot;
    #pragma unroll
    for (int o = 4; o <= 32; o <<= 1) {
      unsigned long long ok = __shfl_xor(key, o);
      double od = __shfl_xor(dotw, o);
      bool take = ok < key;
      key  = take ? ok : key;
      dotw = take ? od : dotw;
    }
    int win = (int)(key & 16383u);
    // outputs (element layout; whole wave)
    float zf = z[(size_t)row * D_DIM + lane];
    float be = e[(size_t)win * D_DIM + lane];
    out[(size_t)row * D_DIM + lane] = zf + (be - zf);   // fp32 op-order ST
    if (lane == 0) {
      out[(size_t)L_TOK * D_DIM + 1 + row] = (float)win;
      wl += zsq64[row] + esq64[win] - 2.0 * dotw;       // ||z - e_win||^2 (fp64)
    }
  }
  if (lane == 0) sp[wave] = wl;
  __syncthreads();
  if (tid == 0) {
    double t = 0.0;
    #pragma unroll
    for (int w = 0; w < 8; ++w) t += sp[w];
    partials[blockIdx.x] = t;
  }
}

// ---------------- kernel 4: finalize loss (1024 partials) --------------------
__global__ __launch_bounds__(512) void vq_loss(const double* __restrict__ partials,
                                               float* __restrict__ out) {
  int tid = threadIdx.x;
  double v = partials[tid] + partials[tid + 512];
  #pragma unroll
  for (int o = 32; o; o >>= 1) v += __shfl_xor(v, o);
  __shared__ double sp[8];
  if ((tid & 63) == 0) sp[tid >> 6] = v;
  __syncthreads();
  if (tid == 0) {
    double tot = 0.0;
    #pragma unroll
    for (int w = 0; w < 8; ++w) tot += sp[w];
    // loss = beta*mean + mean = 1.25 * mean((z_q - z)^2)
    out[(size_t)L_TOK * D_DIM] = (float)(1.25 * tot / (double)((size_t)L_TOK * D_DIM));
  }
}

extern "C" void kernel_launch(void* const* d_in, const int* in_sizes, int n_in,
                              void* d_out, int out_size, void* d_ws, size_t ws_size,
                              hipStream_t stream) {
  const float* z = (const float*)d_in[0];       // (32768, 64) fp32
  const float* e = (const float*)d_in[1];       // (16384, 64) fp32
  float* out = (float*)d_out;                   // [z_q_st | loss | indices-as-f32]
  char* ws = (char*)d_ws;                       // needs ~4.7 MB

  ushort_t* ehi   = (ushort_t*)(ws + WS_EHI);
  float*    esq32 = (float*)(ws + WS_ESQ32);
  float*    esqs  = (float*)(ws + WS_ESQS);
  double*   esq64 = (double*)(ws + WS_ESQ64);
  float*    zsq32 = (float*)(ws + WS_ZSQ32);
  double*   zsq64 = (double*)(ws + WS_ZSQ64);
  int*      cand  = (int*)(ws + WS_CAND);
  double*   parts = (double*)(ws + WS_PART);

  vq_prep_e<<<NE / 4, 256, 0, stream>>>(e, ehi, esq32, esqs, esq64);
  vq_prep_z<<<L_TOK / 4, 256, 0, stream>>>(z, zsq32, zsq64);
  vq_argmin<<<dim3(GCHUNKS, L_TOK / BROWS), 512, 0, stream>>>(z, ehi, esqs, cand);
  vq_refine<<<L_TOK / 32, 512, 0, stream>>>(z, e, esq32, esq64, zsq32, zsq64,
                                            cand, out, parts);
  vq_loss<<<1, 512, 0, stream>>>(parts, out);
}

// Round 6
// 236.892 us; speedup vs baseline: 15.6531x; 1.1241x over previous
//
#include <hip/hip_runtime.h>
#include <cstdint>
#include <cstddef>

// Problem constants (VectorQuantizer: L=32768, D=64, N_E=16384, beta=0.25)
#define L_TOK 32768
#define D_DIM 64
#define NE    16384
#define GCHUNKS 4              // N split across grid
#define NPB   (NE / GCHUNKS)   // 4096 n per block
#define BN    256              // n per LDS stage chunk
#define WROWS 32               // rows per wave (2 MFMA row-groups)
#define BROWS 256              // rows per block (8 waves x 32)

#define SCALE_F 16777216.0f    // 2^24 (exact fp32 scaling)
#define KBIAS_F 131072.0f      // 2^17, folded into esqs at prep

typedef unsigned short ushort_t;
typedef __attribute__((ext_vector_type(8))) short bf16x8;
typedef __attribute__((ext_vector_type(4))) float f32x4;

// ---- ws layout (bytes) ----
#define WS_EHI   0u                                  // 2 MB   e bf16(RNE) permuted
#define WS_ESQ32 (2u<<20)                            // 64 KB  esq np-exact fp32
#define WS_ESQS  ((2u<<20) + (64u<<10))              // 64 KB  esq*0.5*2^24 + 2^17
#define WS_ESQ64 ((2u<<20) + (128u<<10))             // 128 KB esq fp64 (loss)
#define WS_CAND  ((2u<<20) + (256u<<10))             // 2 MB   cand[4][L][4] int
#define WS_PART  ((4u<<20) + (256u<<10))             // 8 KB   loss partials (1024 dbl)

__device__ __forceinline__ ushort_t bf16_rne(float v) {
  unsigned u = __float_as_uint(v);
  return (ushort_t)((u + 0x7fffu + ((u >> 16) & 1u)) >> 16);
}

// numpy pairwise_sum emulation for n=64 contiguous fp32 (scalar 8-acc path).
__device__ __forceinline__ float np_sum64(float a) {
  int j = threadIdx.x & 7;
  float r = __shfl(a, j);
  #pragma unroll
  for (int m = 1; m < 8; ++m) r += __shfl(a, j + 8 * m);
  float s0 = __shfl(r, 0), s1 = __shfl(r, 1), s2 = __shfl(r, 2), s3 = __shfl(r, 3);
  float s4 = __shfl(r, 4), s5 = __shfl(r, 5), s6 = __shfl(r, 6), s7 = __shfl(r, 7);
  return ((s0 + s1) + (s2 + s3)) + ((s4 + s5) + (s6 + s7));
}

// Fragment-permuted index (in ushorts) for element (n, k) — LDS staging order
// equals MFMA B-fragment consumption order (conflict-free ds_read_b128).
__device__ __forceinline__ int perm_off(int n, int k) {
  int tile = n >> 4, c = n & 15, s = k >> 5, q = (k >> 3) & 3, j = k & 7;
  return tile * 1024 + s * 512 + (q * 16 + c) * 8 + j;
}

// ---------------- kernel 1: prep embedding -----------------------------------
__global__ __launch_bounds__(256) void vq_prep_e(const float* __restrict__ e,
                                                 ushort_t* __restrict__ ehi,
                                                 float* __restrict__ esq32,
                                                 float* __restrict__ esqs,
                                                 double* __restrict__ esq64) {
  int wave = threadIdx.x >> 6, lane = threadIdx.x & 63;
  int row = blockIdx.x * 4 + wave;            // one wave per embedding row
  float v = e[(size_t)row * D_DIM + lane];
  ehi[perm_off(row, lane)] = bf16_rne(v);
  float esq = np_sum64(v * v);                // numpy-bit-exact sum(e*e, axis=1)
  double p = (double)v * (double)v;
  #pragma unroll
  for (int o = 32; o; o >>= 1) p += __shfl_xor(p, o);
  if (lane == 0) {
    esq32[row] = esq;                                  // exact rescore
    esqs[row]  = (esq * 0.5f) * SCALE_F + KBIAS_F;     // pre-biased sieve constant
    esq64[row] = p;                                    // loss
  }
}

// ---------------- kernel 2: fused distance + per-row top-k sieve -------------
// grid = dim3(GCHUNKS, L/BROWS), block = 512 (8 waves x 32 rows each)
// Pure-bf16 sieve; packed sort-key:
// (trunc((esq/2 - dot)*2^24 + 2^17) << 14) | n  — positive by Cauchy-Schwarz
// (|dot|*2^24 < 9e4 < 2^17); ties break toward lower n, matching np.argmin.
// 32 rows/wave: each B-tile ds_read feeds 4 MFMAs (halves LDS read/pair).
__global__ __launch_bounds__(512, 4) void vq_argmin(const float* __restrict__ z,
                                                    const ushort_t* __restrict__ ehi,
                                                    const float* __restrict__ esqs,
                                                    int* __restrict__ cand) {
  __shared__ __align__(16) unsigned char smem[49152]; // staging 33KB / merge 48KB
  ushort_t* s_ehi = (ushort_t*)smem;
  float*    s_esq = (float*)(smem + 32768);

  const int tid = threadIdx.x;
  const int wave = tid >> 6, lane = tid & 63;
  const int q = lane >> 4, c = lane & 15;
  const int row0 = blockIdx.y * BROWS + wave * WROWS;
  const int nbase = blockIdx.x * NPB;

  // A fragments: two row-groups of 16, bf16(RNE) in-register.
  // A layout: lane holds A[m=lane&15][k = q*8 + j (+32 for k-step 1)]
  bf16x8 zA[2][2];
  #pragma unroll
  for (int g = 0; g < 2; ++g) {
    const float* zr = z + (size_t)(row0 + g * 16 + c) * D_DIM;
    float4 a0 = *(const float4*)(zr + q * 8);
    float4 a1 = *(const float4*)(zr + q * 8 + 4);
    float4 a2 = *(const float4*)(zr + 32 + q * 8);
    float4 a3 = *(const float4*)(zr + 32 + q * 8 + 4);
    zA[g][0][0] = (short)bf16_rne(a0.x); zA[g][0][1] = (short)bf16_rne(a0.y);
    zA[g][0][2] = (short)bf16_rne(a0.z); zA[g][0][3] = (short)bf16_rne(a0.w);
    zA[g][0][4] = (short)bf16_rne(a1.x); zA[g][0][5] = (short)bf16_rne(a1.y);
    zA[g][0][6] = (short)bf16_rne(a1.z); zA[g][0][7] = (short)bf16_rne(a1.w);
    zA[g][1][0] = (short)bf16_rne(a2.x); zA[g][1][1] = (short)bf16_rne(a2.y);
    zA[g][1][2] = (short)bf16_rne(a2.z); zA[g][1][3] = (short)bf16_rne(a2.w);
    zA[g][1][4] = (short)bf16_rne(a3.x); zA[g][1][5] = (short)bf16_rne(a3.y);
    zA[g][1][6] = (short)bf16_rne(a3.z); zA[g][1][7] = (short)bf16_rne(a3.w);
  }

  const f32x4 fzero = {0.f, 0.f, 0.f, 0.f};  // persistent zero C operand

  // per-(rowgroup g, acc row r) top-3 packed-key tracking (24 VGPRs)
  unsigned K0[2][4], K1[2][4], K2[2][4];
  #pragma unroll
  for (int g = 0; g < 2; ++g)
    #pragma unroll
    for (int r = 0; r < 4; ++r) {
      K0[g][r] = 0xFFFFFFFFu; K1[g][r] = 0xFFFFFFFFu; K2[g][r] = 0xFFFFFFFFu;
    }

  for (int cb = 0; cb < NPB / BN; ++cb) {
    int nch = nbase + cb * BN;
    __syncthreads();   // previous chunk's LDS reads done
    {
      const uint4* gh = ((const uint4*)ehi) + (size_t)nch * 8;  // 8 uint4 per n
      uint4* sb = (uint4*)s_ehi;
      uint4 v0 = gh[tid], v1 = gh[tid + 512], v2 = gh[tid + 1024], v3 = gh[tid + 1536];
      sb[tid] = v0; sb[tid + 512] = v1; sb[tid + 1024] = v2; sb[tid + 1536] = v3;
      if (tid < BN) s_esq[tid] = esqs[nch + tid];
    }
    __syncthreads();

    #pragma unroll 4
    for (int t = 0; t < BN / 16; ++t) {
      const bf16x8 bh0 = *(const bf16x8*)(s_ehi + t * 1024 + lane * 8);
      const bf16x8 bh1 = *(const bf16x8*)(s_ehi + t * 1024 + 512 + lane * 8);
      float esqv = s_esq[t * 16 + c];             // pre-scaled + pre-biased
      unsigned nv = (unsigned)(nch + t * 16 + c);
      f32x4 acc0 = __builtin_amdgcn_mfma_f32_16x16x32_bf16(zA[0][0], bh0, fzero, 0, 0, 0);
      acc0 = __builtin_amdgcn_mfma_f32_16x16x32_bf16(zA[0][1], bh1, acc0, 0, 0, 0);
      f32x4 acc1 = __builtin_amdgcn_mfma_f32_16x16x32_bf16(zA[1][0], bh0, fzero, 0, 0, 0);
      acc1 = __builtin_amdgcn_mfma_f32_16x16x32_bf16(zA[1][1], bh1, acc1, 0, 0, 0);
      #pragma unroll
      for (int r = 0; r < 4; ++r) {
        unsigned qi = (unsigned)fmaf(acc0[r], -SCALE_F, esqv);  // trunc, positive
        unsigned pk = (qi << 14) | nv;
        K2[0][r] = min(max(pk, K1[0][r]), K2[0][r]);
        K1[0][r] = min(max(pk, K0[0][r]), K1[0][r]);
        K0[0][r] = min(pk, K0[0][r]);
      }
      #pragma unroll
      for (int r = 0; r < 4; ++r) {
        unsigned qi = (unsigned)fmaf(acc1[r], -SCALE_F, esqv);
        unsigned pk = (qi << 14) | nv;
        K2[1][r] = min(max(pk, K1[1][r]), K2[1][r]);
        K1[1][r] = min(max(pk, K0[1][r]), K1[1][r]);
        K0[1][r] = min(pk, K0[1][r]);
      }
    }
  }

  // merge 16 lanes' top-3 -> per-row top-4 for this chunk
  __syncthreads();
  unsigned* s_k = (unsigned*)smem;             // [256 rows][16 c][3] = 48 KB
  #pragma unroll
  for (int g = 0; g < 2; ++g)
    #pragma unroll
    for (int r = 0; r < 4; ++r) {
      int rowidx = wave * WROWS + g * 16 + q * 4 + r;  // C layout: row = q*4 + reg
      int base = (rowidx * 16 + c) * 3;
      s_k[base + 0] = K0[g][r]; s_k[base + 1] = K1[g][r]; s_k[base + 2] = K2[g][r];
    }
  __syncthreads();
  if (tid < BROWS) {
    unsigned M0 = 0xFFFFFFFFu, M1 = 0xFFFFFFFFu, M2 = 0xFFFFFFFFu, M3 = 0xFFFFFFFFu;
    const uint4* sv = (const uint4*)(s_k + tid * 48);
    #pragma unroll
    for (int v4 = 0; v4 < 12; ++v4) {
      uint4 kk = sv[v4];
      unsigned vals[4] = {kk.x, kk.y, kk.z, kk.w};
      #pragma unroll
      for (int u = 0; u < 4; ++u) {
        unsigned v = vals[u];
        M3 = min(max(v, M2), M3);
        M2 = min(max(v, M1), M2);
        M1 = min(max(v, M0), M1);
        M0 = min(v, M0);
      }
    }
    int grow = blockIdx.y * BROWS + tid;
    int* cp = cand + ((size_t)blockIdx.x * L_TOK + grow) * 4;
    cp[0] = (int)(M0 & 16383u); cp[1] = (int)(M1 & 16383u);
    cp[2] = (int)(M2 & 16383u); cp[3] = (int)(M3 & 16383u);
  }
}

// ------- kernel 3: np-fp32-exact rescore of 16 candidates, outputs ----------
// grid = L/32 blocks, block 512 (8 waves); each wave: 4 rows, 4 lanes/candidate.
// zsq (np-exact fp32 + fp64) computed inline from the row the wave holds.
__global__ __launch_bounds__(512, 4) void vq_refine(const float* __restrict__ z,
                                                    const float* __restrict__ e,
                                                    const float* __restrict__ esq32,
                                                    const double* __restrict__ esq64,
                                                    const int* __restrict__ cand,
                                                    float* __restrict__ out,
                                                    double* __restrict__ partials) {
  const int tid = threadIdx.x;
  const int wave = tid >> 6, lane = tid & 63;
  const int g = lane >> 2, s = lane & 3;      // 16 cand-groups x 4 lanes
  __shared__ double sp[8];
  double wl = 0.0;
  for (int it = 0; it < 4; ++it) {
    int row = blockIdx.x * 32 + wave * 4 + it;
    float zf = z[(size_t)row * D_DIM + lane];
    float zsqv = np_sum64(zf * zf);            // numpy-bit-exact sum(z*z, axis=1)
    double zp64 = (double)zf * (double)zf;
    #pragma unroll
    for (int o = 32; o; o >>= 1) zp64 += __shfl_xor(zp64, o);
    int idx = cand[((size_t)(g >> 2) * L_TOK + row) * 4 + (g & 3)];
    // fp64 dot over 16 elements/lane, then 2-step in-group reduce
    const float4* ep = (const float4*)(e + (size_t)idx * D_DIM + s * 16);
    const float4* zp = (const float4*)(z + (size_t)row * D_DIM + s * 16);
    double dot = 0.0;
    #pragma unroll
    for (int j = 0; j < 4; ++j) {
      float4 ev = ep[j], zv = zp[j];
      dot = fma((double)ev.x, (double)zv.x, dot);
      dot = fma((double)ev.y, (double)zv.y, dot);
      dot = fma((double)ev.z, (double)zv.z, dot);
      dot = fma((double)ev.w, (double)zv.w, dot);
    }
    dot += __shfl_xor(dot, 1);
    dot += __shfl_xor(dot, 2);
    // emulate np fp32: d = fl32( fl32(zsq + esq) - fl32(2*dot) )
    float t2 = (float)(2.0 * dot);
    float T1 = zsqv + esq32[idx];
    float d  = T1 - t2;                        // d ~ 64 > 0: bits are monotone
    unsigned long long key = ((unsigned long long)__float_as_uint(d) << 14)
                           | (unsigned)idx;    // tie -> lower idx (np.argmin)
    double dotw = dot;
    #pragma unroll
    for (int o = 4; o <= 32; o <<= 1) {
      unsigned long long ok = __shfl_xor(key, o);
      double od = __shfl_xor(dotw, o);
      bool take = ok < key;
      key  = take ? ok : key;
      dotw = take ? od : dotw;
    }
    int win = (int)(key & 16383u);
    // outputs (element layout; whole wave)
    float be = e[(size_t)win * D_DIM + lane];
    out[(size_t)row * D_DIM + lane] = zf + (be - zf);   // fp32 op-order ST
    if (lane == 0) {
      out[(size_t)L_TOK * D_DIM + 1 + row] = (float)win;
      wl += zp64 + esq64[win] - 2.0 * dotw;             // ||z - e_win||^2 (fp64)
    }
  }
  if (lane == 0) sp[wave] = wl;
  __syncthreads();
  if (tid == 0) {
    double t = 0.0;
    #pragma unroll
    for (int w = 0; w < 8; ++w) t += sp[w];
    partials[blockIdx.x] = t;
  }
}

// ---------------- kernel 4: finalize loss (1024 partials) --------------------
__global__ __launch_bounds__(512) void vq_loss(const double* __restrict__ partials,
                                               float* __restrict__ out) {
  int tid = threadIdx.x;
  double v = partials[tid] + partials[tid + 512];
  #pragma unroll
  for (int o = 32; o; o >>= 1) v += __shfl_xor(v, o);
  __shared__ double sp[8];
  if ((tid & 63) == 0) sp[tid >> 6] = v;
  __syncthreads();
  if (tid == 0) {
    double tot = 0.0;
    #pragma unroll
    for (int w = 0; w < 8; ++w) tot += sp[w];
    // loss = beta*mean + mean = 1.25 * mean((z_q - z)^2)
    out[(size_t)L_TOK * D_DIM] = (float)(1.25 * tot / (double)((size_t)L_TOK * D_DIM));
  }
}

extern "C" void kernel_launch(void* const* d_in, const int* in_sizes, int n_in,
                              void* d_out, int out_size, void* d_ws, size_t ws_size,
                              hipStream_t stream) {
  const float* z = (const float*)d_in[0];       // (32768, 64) fp32
  const float* e = (const float*)d_in[1];       // (16384, 64) fp32
  float* out = (float*)d_out;                   // [z_q_st | loss | indices-as-f32]
  char* ws = (char*)d_ws;                       // needs ~4.3 MB

  ushort_t* ehi   = (ushort_t*)(ws + WS_EHI);
  float*    esq32 = (float*)(ws + WS_ESQ32);
  float*    esqs  = (float*)(ws + WS_ESQS);
  double*   esq64 = (double*)(ws + WS_ESQ64);
  int*      cand  = (int*)(ws + WS_CAND);
  double*   parts = (double*)(ws + WS_PART);

  vq_prep_e<<<NE / 4, 256, 0, stream>>>(e, ehi, esq32, esqs, esq64);
  vq_argmin<<<dim3(GCHUNKS, L_TOK / BROWS), 512, 0, stream>>>(z, ehi, esqs, cand);
  vq_refine<<<L_TOK / 32, 512, 0, stream>>>(z, e, esq32, esq64, cand, out, parts);
  vq_loss<<<1, 512, 0, stream>>>(parts, out);
}

// Round 7
// 221.037 us; speedup vs baseline: 16.7759x; 1.0717x over previous
//
#include <hip/hip_runtime.h>
#include <cstdint>
#include <cstddef>

// Problem constants (VectorQuantizer: L=32768, D=64, N_E=16384, beta=0.25)
#define L_TOK 32768
#define D_DIM 64
#define NE    16384
#define GCHUNKS 4              // N split across grid
#define NPB   (NE / GCHUNKS)   // 4096 n per block
#define BN    256              // n per LDS stage chunk
#define WROWS 32               // rows per wave (2 MFMA row-groups)
#define BROWS 256              // rows per block (8 waves x 32)

#define ASCALE  -4194304.0f    // -2^22: A-fragment pre-scale (exact pow2)
#define ESCALE   2097152.0f    // 2^21 = 0.5*2^22 for esq
#define KBIAS_F  32768.0f      // 2^15 bias, folded into esqs at prep

typedef unsigned short ushort_t;
typedef __attribute__((ext_vector_type(8))) short bf16x8;
typedef __attribute__((ext_vector_type(4))) float f32x4;

// ---- ws layout (bytes) ----
#define WS_EHI   0u                                  // 2 MB   e bf16(RNE) permuted
#define WS_ESQ32 (2u<<20)                            // 64 KB  esq np-exact fp32
#define WS_ESQS  ((2u<<20) + (64u<<10))              // 64 KB  esq*2^21 + 2^15
#define WS_ESQ64 ((2u<<20) + (128u<<10))             // 128 KB esq fp64 (loss)
#define WS_CAND  ((2u<<20) + (256u<<10))             // 2 MB   cand[4][L][4] int
#define WS_PART  ((4u<<20) + (256u<<10))             // 8 KB   loss partials (1024 dbl)

__device__ __forceinline__ ushort_t bf16_rne(float v) {
  unsigned u = __float_as_uint(v);
  return (ushort_t)((u + 0x7fffu + ((u >> 16) & 1u)) >> 16);
}

// v_med3_u32: median(a,b,c). With b<=c this equals min(max(a,b),c) — the
// top-k insertion step. The compiler can't prove the invariant, so ask for
// the instruction directly.
__device__ __forceinline__ unsigned umed3(unsigned a, unsigned b, unsigned c) {
  unsigned d;
  asm("v_med3_u32 %0, %1, %2, %3" : "=v"(d) : "v"(a), "v"(b), "v"(c));
  return d;
}

// numpy pairwise_sum emulation for n=64 contiguous fp32 (scalar 8-acc path).
__device__ __forceinline__ float np_sum64(float a) {
  int j = threadIdx.x & 7;
  float r = __shfl(a, j);
  #pragma unroll
  for (int m = 1; m < 8; ++m) r += __shfl(a, j + 8 * m);
  float s0 = __shfl(r, 0), s1 = __shfl(r, 1), s2 = __shfl(r, 2), s3 = __shfl(r, 3);
  float s4 = __shfl(r, 4), s5 = __shfl(r, 5), s6 = __shfl(r, 6), s7 = __shfl(r, 7);
  return ((s0 + s1) + (s2 + s3)) + ((s4 + s5) + (s6 + s7));
}

// Fragment-permuted index (in ushorts) for element (n, k) — LDS staging order
// equals MFMA B-fragment consumption order (conflict-free ds_read_b128).
__device__ __forceinline__ int perm_off(int n, int k) {
  int tile = n >> 4, c = n & 15, s = k >> 5, q = (k >> 3) & 3, j = k & 7;
  return tile * 1024 + s * 512 + (q * 16 + c) * 8 + j;
}

// ---------------- kernel 1: prep embedding -----------------------------------
__global__ __launch_bounds__(256) void vq_prep_e(const float* __restrict__ e,
                                                 ushort_t* __restrict__ ehi,
                                                 float* __restrict__ esq32,
                                                 float* __restrict__ esqs,
                                                 double* __restrict__ esq64) {
  int wave = threadIdx.x >> 6, lane = threadIdx.x & 63;
  int row = blockIdx.x * 4 + wave;            // one wave per embedding row
  float v = e[(size_t)row * D_DIM + lane];
  ehi[perm_off(row, lane)] = bf16_rne(v);
  float esq = np_sum64(v * v);                // numpy-bit-exact sum(e*e, axis=1)
  double p = (double)v * (double)v;
  #pragma unroll
  for (int o = 32; o; o >>= 1) p += __shfl_xor(p, o);
  if (lane == 0) {
    esq32[row] = esq;                         // exact rescore
    esqs[row]  = esq * ESCALE + KBIAS_F;      // sieve MFMA C operand
    esq64[row] = p;                           // loss
  }
}

// ---------------- kernel 2: fused distance + per-row top-k sieve -------------
// grid = dim3(GCHUNKS, L/BROWS), block = 512 (8 waves x 32 rows each)
// A is pre-scaled by -2^22 and esq*2^21+2^15 rides in as the MFMA C operand,
// so the accumulator directly equals the sieve key 2^22*d + 2^15 (positive by
// Cauchy-Schwarz: |dot|*2^22 < 24k < 2^15).  Packed key:
// (trunc(acc) << 12) | (tile*16 + c)  — 16-bit magnitude (2.4e-7 buckets in d,
// << the ~1e-5 np-fp32 window the refine resolves), ties break toward lower n.
__global__ __launch_bounds__(512, 4) void vq_argmin(const float* __restrict__ z,
                                                    const ushort_t* __restrict__ ehi,
                                                    const float* __restrict__ esqs,
                                                    int* __restrict__ cand) {
  __shared__ __align__(16) unsigned char smem[49152]; // staging 33KB / merge 48KB
  ushort_t* s_ehi = (ushort_t*)smem;
  float*    s_esq = (float*)(smem + 32768);

  const int tid = threadIdx.x;
  const int wave = tid >> 6, lane = tid & 63;
  const int q = lane >> 4, c = lane & 15;
  const int row0 = blockIdx.y * BROWS + wave * WROWS;
  const int nbase = blockIdx.x * NPB;

  // A fragments: two row-groups of 16, bf16(RNE) of -2^22*z in-register.
  // A layout: lane holds A[m=lane&15][k = q*8 + j (+32 for k-step 1)]
  bf16x8 zA[2][2];
  #pragma unroll
  for (int g = 0; g < 2; ++g) {
    const float* zr = z + (size_t)(row0 + g * 16 + c) * D_DIM;
    float4 a0 = *(const float4*)(zr + q * 8);
    float4 a1 = *(const float4*)(zr + q * 8 + 4);
    float4 a2 = *(const float4*)(zr + 32 + q * 8);
    float4 a3 = *(const float4*)(zr + 32 + q * 8 + 4);
    zA[g][0][0] = (short)bf16_rne(a0.x * ASCALE); zA[g][0][1] = (short)bf16_rne(a0.y * ASCALE);
    zA[g][0][2] = (short)bf16_rne(a0.z * ASCALE); zA[g][0][3] = (short)bf16_rne(a0.w * ASCALE);
    zA[g][0][4] = (short)bf16_rne(a1.x * ASCALE); zA[g][0][5] = (short)bf16_rne(a1.y * ASCALE);
    zA[g][0][6] = (short)bf16_rne(a1.z * ASCALE); zA[g][0][7] = (short)bf16_rne(a1.w * ASCALE);
    zA[g][1][0] = (short)bf16_rne(a2.x * ASCALE); zA[g][1][1] = (short)bf16_rne(a2.y * ASCALE);
    zA[g][1][2] = (short)bf16_rne(a2.z * ASCALE); zA[g][1][3] = (short)bf16_rne(a2.w * ASCALE);
    zA[g][1][4] = (short)bf16_rne(a3.x * ASCALE); zA[g][1][5] = (short)bf16_rne(a3.y * ASCALE);
    zA[g][1][6] = (short)bf16_rne(a3.z * ASCALE); zA[g][1][7] = (short)bf16_rne(a3.w * ASCALE);
  }

  // per-(rowgroup g, acc row r) top-3 packed-key tracking (24 VGPRs),
  // invariant K0 <= K1 <= K2 (init equal, preserved by med3 insertion)
  unsigned K0[2][4], K1[2][4], K2[2][4];
  #pragma unroll
  for (int g = 0; g < 2; ++g)
    #pragma unroll
    for (int r = 0; r < 4; ++r) {
      K0[g][r] = 0xFFFFFFFFu; K1[g][r] = 0xFFFFFFFFu; K2[g][r] = 0xFFFFFFFFu;
    }

  for (int cb = 0; cb < NPB / BN; ++cb) {
    int nch = nbase + cb * BN;
    __syncthreads();   // previous chunk's LDS reads done
    {
      const uint4* gh = ((const uint4*)ehi) + (size_t)nch * 8;  // 8 uint4 per n
      uint4* sb = (uint4*)s_ehi;
      uint4 v0 = gh[tid], v1 = gh[tid + 512], v2 = gh[tid + 1024], v3 = gh[tid + 1536];
      sb[tid] = v0; sb[tid + 512] = v1; sb[tid + 1024] = v2; sb[tid + 1536] = v3;
      if (tid < BN) s_esq[tid] = esqs[nch + tid];
    }
    __syncthreads();

    #pragma unroll 4
    for (int t = 0; t < BN / 16; ++t) {
      const bf16x8 bh0 = *(const bf16x8*)(s_ehi + t * 1024 + lane * 8);
      const bf16x8 bh1 = *(const bf16x8*)(s_ehi + t * 1024 + 512 + lane * 8);
      float esqv = s_esq[t * 16 + c];
      f32x4 cvec = {esqv, esqv, esqv, esqv};       // key bias rides in as C
      unsigned tcv = (((unsigned)(cb * 16 + t)) << 4) | (unsigned)c;  // n_local
      f32x4 acc0 = __builtin_amdgcn_mfma_f32_16x16x32_bf16(zA[0][0], bh0, cvec, 0, 0, 0);
      acc0 = __builtin_amdgcn_mfma_f32_16x16x32_bf16(zA[0][1], bh1, acc0, 0, 0, 0);
      f32x4 acc1 = __builtin_amdgcn_mfma_f32_16x16x32_bf16(zA[1][0], bh0, cvec, 0, 0, 0);
      acc1 = __builtin_amdgcn_mfma_f32_16x16x32_bf16(zA[1][1], bh1, acc1, 0, 0, 0);
      #pragma unroll
      for (int r = 0; r < 4; ++r) {
        unsigned pk = (((unsigned)acc0[r]) << 12) | tcv;   // cvt + lshl_or
        K2[0][r] = umed3(pk, K1[0][r], K2[0][r]);
        K1[0][r] = umed3(pk, K0[0][r], K1[0][r]);
        K0[0][r] = min(pk, K0[0][r]);
      }
      #pragma unroll
      for (int r = 0; r < 4; ++r) {
        unsigned pk = (((unsigned)acc1[r]) << 12) | tcv;
        K2[1][r] = umed3(pk, K1[1][r], K2[1][r]);
        K1[1][r] = umed3(pk, K0[1][r], K1[1][r]);
        K0[1][r] = min(pk, K0[1][r]);
      }
    }
  }

  // merge 16 lanes' top-3 -> per-row top-4 for this chunk
  __syncthreads();
  unsigned* s_k = (unsigned*)smem;             // [256 rows][16 c][3] = 48 KB
  #pragma unroll
  for (int g = 0; g < 2; ++g)
    #pragma unroll
    for (int r = 0; r < 4; ++r) {
      int rowidx = wave * WROWS + g * 16 + q * 4 + r;  // C layout: row = q*4 + reg
      int base = (rowidx * 16 + c) * 3;
      s_k[base + 0] = K0[g][r]; s_k[base + 1] = K1[g][r]; s_k[base + 2] = K2[g][r];
    }
  __syncthreads();
  if (tid < BROWS) {
    unsigned M0 = 0xFFFFFFFFu, M1 = 0xFFFFFFFFu, M2 = 0xFFFFFFFFu, M3 = 0xFFFFFFFFu;
    const uint4* sv = (const uint4*)(s_k + tid * 48);
    #pragma unroll
    for (int v4 = 0; v4 < 12; ++v4) {
      uint4 kk = sv[v4];
      unsigned vals[4] = {kk.x, kk.y, kk.z, kk.w};
      #pragma unroll
      for (int u = 0; u < 4; ++u) {
        unsigned v = vals[u];
        M3 = umed3(v, M2, M3);
        M2 = umed3(v, M1, M2);
        M1 = umed3(v, M0, M1);
        M0 = min(v, M0);
      }
    }
    int grow = blockIdx.y * BROWS + tid;
    int* cp = cand + ((size_t)blockIdx.x * L_TOK + grow) * 4;
    cp[0] = (int)(nbase + (M0 & 4095u)); cp[1] = (int)(nbase + (M1 & 4095u));
    cp[2] = (int)(nbase + (M2 & 4095u)); cp[3] = (int)(nbase + (M3 & 4095u));
  }
}

// ------- kernel 3: np-fp32-exact rescore of 16 candidates, outputs ----------
// grid = L/32 blocks, block 512 (8 waves); each wave: 4 rows, 4 lanes/candidate.
// zsq (np-exact fp32 + fp64) computed inline from the row the wave holds.
__global__ __launch_bounds__(512, 4) void vq_refine(const float* __restrict__ z,
                                                    const float* __restrict__ e,
                                                    const float* __restrict__ esq32,
                                                    const double* __restrict__ esq64,
                                                    const int* __restrict__ cand,
                                                    float* __restrict__ out,
                                                    double* __restrict__ partials) {
  const int tid = threadIdx.x;
  const int wave = tid >> 6, lane = tid & 63;
  const int g = lane >> 2, s = lane & 3;      // 16 cand-groups x 4 lanes
  __shared__ double sp[8];
  double wl = 0.0;
  for (int it = 0; it < 4; ++it) {
    int row = blockIdx.x * 32 + wave * 4 + it;
    float zf = z[(size_t)row * D_DIM + lane];
    float zsqv = np_sum64(zf * zf);            // numpy-bit-exact sum(z*z, axis=1)
    double zp64 = (double)zf * (double)zf;
    #pragma unroll
    for (int o = 32; o; o >>= 1) zp64 += __shfl_xor(zp64, o);
    int idx = cand[((size_t)(g >> 2) * L_TOK + row) * 4 + (g & 3)];
    // fp64 dot over 16 elements/lane, then 2-step in-group reduce
    const float4* ep = (const float4*)(e + (size_t)idx * D_DIM + s * 16);
    const float4* zp = (const float4*)(z + (size_t)row * D_DIM + s * 16);
    double dot = 0.0;
    #pragma unroll
    for (int j = 0; j < 4; ++j) {
      float4 ev = ep[j], zv = zp[j];
      dot = fma((double)ev.x, (double)zv.x, dot);
      dot = fma((double)ev.y, (double)zv.y, dot);
      dot = fma((double)ev.z, (double)zv.z, dot);
      dot = fma((double)ev.w, (double)zv.w, dot);
    }
    dot += __shfl_xor(dot, 1);
    dot += __shfl_xor(dot, 2);
    // emulate np fp32: d = fl32( fl32(zsq + esq) - fl32(2*dot) )
    float t2 = (float)(2.0 * dot);
    float T1 = zsqv + esq32[idx];
    float d  = T1 - t2;                        // d ~ 64 > 0: bits are monotone
    unsigned long long key = ((unsigned long long)__float_as_uint(d) << 14)
                           | (unsigned)idx;    // tie -> lower idx (np.argmin)
    double dotw = dot;
    #pragma unroll
    for (int o = 4; o <= 32; o <<= 1) {
      unsigned long long ok = __shfl_xor(key, o);
      double od = __shfl_xor(dotw, o);
      bool take = ok < key;
      key  = take ? ok : key;
      dotw = take ? od : dotw;
    }
    int win = (int)(key & 16383u);
    // outputs (element layout; whole wave)
    float be = e[(size_t)win * D_DIM + lane];
    out[(size_t)row * D_DIM + lane] = zf + (be - zf);   // fp32 op-order ST
    if (lane == 0) {
      out[(size_t)L_TOK * D_DIM + 1 + row] = (float)win;
      wl += zp64 + esq64[win] - 2.0 * dotw;             // ||z - e_win||^2 (fp64)
    }
  }
  if (lane == 0) sp[wave] = wl;
  __syncthreads();
  if (tid == 0) {
    double t = 0.0;
    #pragma unroll
    for (int w = 0; w < 8; ++w) t += sp[w];
    partials[blockIdx.x] = t;
  }
}

// ---------------- kernel 4: finalize loss (1024 partials) --------------------
__global__ __launch_bounds__(512) void vq_loss(const double* __restrict__ partials,
                                               float* __restrict__ out) {
  int tid = threadIdx.x;
  double v = partials[tid] + partials[tid + 512];
  #pragma unroll
  for (int o = 32; o; o >>= 1) v += __shfl_xor(v, o);
  __shared__ double sp[8];
  if ((tid & 63) == 0) sp[tid >> 6] = v;
  __syncthreads();
  if (tid == 0) {
    double tot = 0.0;
    #pragma unroll
    for (int w = 0; w < 8; ++w) tot += sp[w];
    // loss = beta*mean + mean = 1.25 * mean((z_q - z)^2)
    out[(size_t)L_TOK * D_DIM] = (float)(1.25 * tot / (double)((size_t)L_TOK * D_DIM));
  }
}

extern "C" void kernel_launch(void* const* d_in, const int* in_sizes, int n_in,
                              void* d_out, int out_size, void* d_ws, size_t ws_size,
                              hipStream_t stream) {
  const float* z = (const float*)d_in[0];       // (32768, 64) fp32
  const float* e = (const float*)d_in[1];       // (16384, 64) fp32
  float* out = (float*)d_out;                   // [z_q_st | loss | indices-as-f32]
  char* ws = (char*)d_ws;                       // needs ~4.3 MB

  ushort_t* ehi   = (ushort_t*)(ws + WS_EHI);
  float*    esq32 = (float*)(ws + WS_ESQ32);
  float*    esqs  = (float*)(ws + WS_ESQS);
  double*   esq64 = (double*)(ws + WS_ESQ64);
  int*      cand  = (int*)(ws + WS_CAND);
  double*   parts = (double*)(ws + WS_PART);

  vq_prep_e<<<NE / 4, 256, 0, stream>>>(e, ehi, esq32, esqs, esq64);
  vq_argmin<<<dim3(GCHUNKS, L_TOK / BROWS), 512, 0, stream>>>(z, ehi, esqs, cand);
  vq_refine<<<L_TOK / 32, 512, 0, stream>>>(z, e, esq32, esq64, cand, out, parts);
  vq_loss<<<1, 512, 0, stream>>>(parts, out);
}